// Round 10
// baseline (308.888 us; speedup 1.0000x reference)
//
#include <hip/hip_runtime.h>
#include <math.h>

#define BB   2
#define LL   2048
#define HIDD 2048
#define NHH  16
#define HDD  128
#define QKVN 6144   // 3*HIDD
#define THR2 11.5416f  // defer-max threshold, log2 domain (= 8 nats)
#define PSTRIDE 33792  // 32KB partial O + 512B m + 512B l

typedef unsigned short u16;
typedef float  f32x4 __attribute__((ext_vector_type(4)));
typedef __bf16 bf16x8 __attribute__((ext_vector_type(8)));

static __device__ __forceinline__ float exp2_fast(float x){
  return __builtin_amdgcn_exp2f(x);    // v_exp_f32 (native 2^x)
}
static __device__ __forceinline__ u16 f2bf(float x){
  unsigned u = __float_as_uint(x);
  return (u16)((u + 0x7fffu + ((u >> 16) & 1u)) >> 16);
}
static __device__ __forceinline__ float bf2f(u16 b){
  return __uint_as_float(((unsigned)b) << 16);
}
static __device__ __forceinline__ void gl_lds16(const void* g, void* l){
  __builtin_amdgcn_global_load_lds(
      (__attribute__((address_space(1))) void*)(void*)g,
      (__attribute__((address_space(3))) void*)l,
      16, 0, 0);
}

// ---------------- prep kernels ----------------

__global__ void cvt_f32_bf16_k(const float* __restrict__ src, u16* __restrict__ dst, int n4){
  int i = blockIdx.x * blockDim.x + threadIdx.x;
  if (i >= n4) return;
  float4 v = ((const float4*)src)[i];
  ushort4 o;
  o.x = f2bf(v.x); o.y = f2bf(v.y); o.z = f2bf(v.z); o.w = f2bf(v.w);
  ((ushort4*)dst)[i] = o;
}

// src: R x C f32 (row-major) -> dst: C x R bf16
__global__ void transpose_cvt_k(const float* __restrict__ src, u16* __restrict__ dst, int R, int C){
  __shared__ float t[32][33];
  int c0 = blockIdx.x * 32, r0 = blockIdx.y * 32;
  int tx = threadIdx.x, ty = threadIdx.y;
  #pragma unroll
  for (int i = 0; i < 32; i += 8) t[ty + i][tx] = src[(size_t)(r0 + ty + i) * C + c0 + tx];
  __syncthreads();
  #pragma unroll
  for (int i = 0; i < 32; i += 8) dst[(size_t)(c0 + ty + i) * R + r0 + tx] = f2bf(t[tx][ty + i]);
}

// in-place RoPE on q,k sections of qkv (bf16). idx over B*L*NH*64
// Q additionally pre-scaled by 1/sqrt(128)*log2(e) -> scores in exp2 domain.
__global__ void rope_k(u16* __restrict__ qkv){
  int idx = blockIdx.x * blockDim.x + threadIdx.x;
  int d   = idx & 63;
  int h   = (idx >> 6) & 15;
  int row = idx >> 10;           // b*L + l
  int l   = row & (LL - 1);
  float fr = __expf(-(float)d * 0.17988946f);   // ln(1e5)/64
  float th = (float)l * 0.25f * fr;             // pos/ROPE_SCALE * freq
  float s, c;
  sincosf(th, &s, &c);
  size_t base = (size_t)row * QKVN + h * HDD + d;
  #pragma unroll
  for (int part = 0; part < 2; part++){         // q then k
    float f = (part == 0) ? 0.12753375f : 1.0f; // scale*log2e folded into Q
    float x1 = bf2f(qkv[base]), x2 = bf2f(qkv[base + 64]);
    qkv[base]      = f2bf((x1 * c - x2 * s) * f);
    qkv[base + 64] = f2bf((x1 * s + x2 * c) * f);
    base += HIDD;
  }
}

// v section of qkv -> vt[(b,h), d, l]
__global__ void build_vt_k(const u16* __restrict__ qkv, u16* __restrict__ vt){
  __shared__ u16 t[32][33];
  int bh = blockIdx.z;
  int b = bh >> 4, h = bh & 15;
  const u16* src = qkv + (size_t)b * LL * QKVN + 2 * HIDD + h * HDD; // [l][d] stride QKVN
  u16* dst = vt + (size_t)bh * HDD * LL;                              // [d][l] stride LL
  int d0 = blockIdx.x * 32, l0 = blockIdx.y * 32;
  int tx = threadIdx.x, ty = threadIdx.y;
  #pragma unroll
  for (int i = 0; i < 32; i += 8) t[ty + i][tx] = src[(size_t)(l0 + ty + i) * QKVN + d0 + tx];
  __syncthreads();
  #pragma unroll
  for (int i = 0; i < 32; i += 8) dst[(size_t)(d0 + ty + i) * LL + l0 + tx] = t[tx][ty + i];
}

// ---------------- GEMM (round-7 proven): C[M,N] = A[M,K] * Bt[N,K]^T ----------------

template<int OUT_BF16>
__global__ __launch_bounds__(256) void gemm_bt_k(
    const u16* __restrict__ A, const u16* __restrict__ Bt,
    void* __restrict__ Cout, int M, int N, int K)
{
  __shared__ __align__(16) u16 As[128 * 64];
  __shared__ __align__(16) u16 Bs[128 * 64];
  const int tid = threadIdx.x, lane = tid & 63, wv = tid >> 6;
  const int wr = wv >> 1, wc = wv & 1;
  const int m0 = blockIdx.y * 128, n0 = blockIdx.x * 128;
  const int rq = lane >> 4, cl = lane & 15;

  const f32x4 Z = {0.f, 0.f, 0.f, 0.f};
  f32x4 acc[4][4];
  #pragma unroll
  for (int m = 0; m < 4; m++)
    #pragma unroll
    for (int n = 0; n < 4; n++) acc[m][n] = Z;

  for (int kt = 0; kt < K; kt += 64){
    #pragma unroll
    for (int i = 0; i < 4; i++){
      int fb = (i * 4 + wv) * 64;          // wave-uniform 16B-chunk base
      int p  = (fb + lane) * 16;           // this lane's physical LDS byte
      int r  = p >> 7;                     // tile row (128B rows)
      int cbs = (p & 127) ^ ((r & 7) << 4);
      gl_lds16(A  + (size_t)(m0 + r) * K + kt + (cbs >> 1), &As[fb * 8]);
      gl_lds16(Bt + (size_t)(n0 + r) * K + kt + (cbs >> 1), &Bs[fb * 8]);
    }
    __syncthreads();
    #pragma unroll
    for (int ks = 0; ks < 2; ks++){
      const int kb = ks * 64 + rq * 16;    // k byte offset in row
      bf16x8 a[4], b[4];
      #pragma unroll
      for (int m = 0; m < 4; m++){
        int r = wr * 64 + m * 16 + cl;
        a[m] = *(const bf16x8*)((const char*)As + r * 128 + (kb ^ ((r & 7) << 4)));
      }
      #pragma unroll
      for (int n = 0; n < 4; n++){
        int r = wc * 64 + n * 16 + cl;
        b[n] = *(const bf16x8*)((const char*)Bs + r * 128 + (kb ^ ((r & 7) << 4)));
      }
      #pragma unroll
      for (int m = 0; m < 4; m++)
        #pragma unroll
        for (int n = 0; n < 4; n++)
          acc[m][n] = __builtin_amdgcn_mfma_f32_16x16x32_bf16(a[m], b[n], acc[m][n], 0, 0, 0);
    }
    __syncthreads();
  }

  #pragma unroll
  for (int m = 0; m < 4; m++){
    int gr0 = m0 + wr * 64 + m * 16 + rq * 4;
    #pragma unroll
    for (int n = 0; n < 4; n++){
      int gc = n0 + wc * 64 + n * 16 + cl;
      #pragma unroll
      for (int rr = 0; rr < 4; rr++){
        if (OUT_BF16) ((u16*)Cout)[(size_t)(gr0 + rr) * N + gc] = f2bf(acc[m][n][rr]);
        else          ((float*)Cout)[(size_t)(gr0 + rr) * N + gc] = acc[m][n][rr];
      }
    }
  }
}

// ---------------- flash attention v3: split-pair, 4 waves x 32 rows, 2 blocks/CU --------
// grid (bh=32 fast, slot s=0..15), 256 thr. Every block = exactly 17 tile-iters:
//   s<8  (A): long tile qt=15-s, j in [0,17)            -> partial seg 0
//   s>=8 (B): long tile qt=15-p, j in [17,32-2p) (p=s-8) -> partial seg 1
//             then short tile qt=p, j in [0,2p+2)        -> direct write
// K dbuf (2x16KB) + V (16KB) = 48KB; P overlays consumed K; lean softmax
// (exp2 domain, ones-MFMA row-sum, defer-max gate). Long tiles combined after.

#define STAGE_K(jj, bsel) do {                                                            \
  _Pragma("unroll")                                                                       \
  for (int i_ = 0; i_ < 4; i_++){                                                         \
    int fb_ = (i_ * 4 + wv) * 64;                                                         \
    int p_  = (fb_ + lane) * 16;                                                          \
    int r_ = p_ >> 8; int cb_ = (p_ & 255) ^ ((r_ & 7) << 4);                             \
    gl_lds16(qkv + (size_t)(b * LL + (jj) * 64 + r_) * QKVN + HIDD + h * HDD + (cb_ >> 1),\
             &Kb[bsel][fb_ * 8]);                                                         \
  }                                                                                       \
} while(0)

#define STAGE_V(jj) do {                                                                  \
  _Pragma("unroll")                                                                       \
  for (int i_ = 0; i_ < 4; i_++){                                                         \
    int fb_ = (i_ * 4 + wv) * 64;                                                         \
    int p_  = (fb_ + lane) * 16;                                                          \
    int r_ = p_ >> 7; int cb_ = (p_ & 127) ^ ((r_ & 7) << 4);                             \
    gl_lds16(vt + (size_t)(bh * HDD + r_) * LL + (jj) * 64 + (cb_ >> 1), &Vs[fb_ * 8]);   \
  }                                                                                       \
} while(0)

__global__ __launch_bounds__(256, 2) void attn_pair_k(
    const u16* __restrict__ qkv, const u16* __restrict__ vt,
    u16* __restrict__ aout, char* __restrict__ part)
{
  __shared__ __align__(16) u16 Kb[2][64 * 128];   // K tiles [64][128], 2x16KB
  __shared__ __align__(16) u16 Vs[128 * 64];      // V^T tile [128][64], 16KB
  const int tid = threadIdx.x, lane = tid & 63, wv = tid >> 6;
  const int bh = blockIdx.x;                      // fast dim -> XCD = bh % 8
  const int s  = blockIdx.y;                      // slot 0..15
  const int b = bh >> 4, h = bh & 15;
  const int rq = lane >> 4, cl = lane & 15;

  int p, nph, qt0, j00, j01, qt1 = 0, j11 = 0;
  if (s < 8){ p = s;     nph = 1; qt0 = 15 - p; j00 = 0;  j01 = 17; }
  else      { p = s - 8; nph = 2; qt0 = 15 - p; j00 = 17; j01 = 32 - 2 * p;
              qt1 = p; j11 = 2 * p + 2; }

  bf16x8 ones;
  #pragma unroll
  for (int i = 0; i < 8; i++) ones[i] = (__bf16)1.0f;
  const f32x4 Z = {0.f, 0.f, 0.f, 0.f};

  int cur = 0;
  STAGE_K(j00, 0);
  __syncthreads();

  for (int phx = 0; phx < nph; phx++){
    const int qt = (phx == 0) ? qt0 : qt1;
    const int j0 = (phx == 0) ? j00 : 0;
    const int j1 = (phx == 0) ? j01 : j11;

    // Q fragments: rows qt*128 + wv*32 + rt*16 + cl (Q pre-scaled in rope_k)
    bf16x8 qf[2][4];
    #pragma unroll
    for (int rt = 0; rt < 2; rt++){
      const u16* qb = qkv + (size_t)(b * LL + qt * 128 + wv * 32 + rt * 16 + cl) * QKVN + h * HDD + rq * 8;
      #pragma unroll
      for (int ks = 0; ks < 4; ks++) qf[rt][ks] = *(const bf16x8*)(qb + ks * 32);
    }

    f32x4 acco[2][8], accl[2];
    float mst[2][4];
    #pragma unroll
    for (int rt = 0; rt < 2; rt++){
      #pragma unroll
      for (int n = 0; n < 8; n++) acco[rt][n] = Z;
      accl[rt] = Z;
      #pragma unroll
      for (int rr = 0; rr < 4; rr++) mst[rt][rr] = -INFINITY;
    }

    const int wrow_hi = qt * 128 + wv * 32 + 31;

    for (int j = j0; j < j1; j++){
      if (j + 1 < j1)                 STAGE_K(j + 1, cur ^ 1);
      else if (phx == 0 && nph == 2)  STAGE_K(0,     cur ^ 1);  // cross into short tile
      STAGE_V(j);
      const bool act = (j * 64 <= wrow_hi);

      f32x4 sv[2][4];
      if (act){
        const char* KsC = (const char*)&Kb[cur][0];
        #pragma unroll
        for (int rt = 0; rt < 2; rt++)
          #pragma unroll
          for (int ct = 0; ct < 4; ct++) sv[rt][ct] = Z;
        #pragma unroll
        for (int ks = 0; ks < 4; ks++){
          const int kb = ks * 64 + rq * 16;
          #pragma unroll
          for (int ct = 0; ct < 4; ct++){
            int r = ct * 16 + cl;
            bf16x8 bfr = *(const bf16x8*)(KsC + r * 256 + (kb ^ ((r & 7) << 4)));
            #pragma unroll
            for (int rt = 0; rt < 2; rt++)
              sv[rt][ct] = __builtin_amdgcn_mfma_f32_16x16x32_bf16(qf[rt][ks], bfr, sv[rt][ct], 0, 0, 0);
          }
        }
      }

      __syncthreads();   // QK reads of Kb[cur] done; V (and next K) landed

      if (act){
        char* pbase = (char*)&Kb[cur][0] + wv * 4096;   // P overlays consumed K
        const bool msk = (j >= 2 * qt);

        #pragma unroll
        for (int rt = 0; rt < 2; rt++){
          float p4[4][4], lmx[4];
          #pragma unroll
          for (int rr = 0; rr < 4; rr++) lmx[rr] = -1e30f;
          const int qg = qt * 128 + wv * 32 + rt * 16 + rq * 4;
          #pragma unroll
          for (int ct = 0; ct < 4; ct++){
            int col = j * 64 + ct * 16 + cl;
            #pragma unroll
            for (int rr = 0; rr < 4; rr++){
              float v = sv[rt][ct][rr];               // already log2-domain
              if (msk && col > qg + rr) v = -1e30f;
              p4[ct][rr] = v;
              lmx[rr] = fmaxf(lmx[rr], v);
            }
          }
          float need = -1e30f;
          #pragma unroll
          for (int rr = 0; rr < 4; rr++) need = fmaxf(need, lmx[rr] - mst[rt][rr]);
          if (__any(need > THR2)){
            float mx[4];
            #pragma unroll
            for (int rr = 0; rr < 4; rr++) mx[rr] = lmx[rr];
            #pragma unroll
            for (int off = 1; off < 16; off <<= 1)
              #pragma unroll
              for (int rr = 0; rr < 4; rr++)
                mx[rr] = fmaxf(mx[rr], __shfl_xor(mx[rr], off, 64));
            #pragma unroll
            for (int rr = 0; rr < 4; rr++){
              float mn  = fmaxf(mst[rt][rr], mx[rr]);
              float fsc = exp2_fast(mst[rt][rr] - mn);
              mst[rt][rr] = mn;
              accl[rt][rr] *= fsc;
              #pragma unroll
              for (int n = 0; n < 8; n++) acco[rt][n][rr] *= fsc;
            }
          }
          #pragma unroll
          for (int ct = 0; ct < 4; ct++)
            #pragma unroll
            for (int rr = 0; rr < 4; rr++){
              float e = exp2_fast(p4[ct][rr] - mst[rt][rr]);
              int wr = rt * 16 + rq * 4 + rr;
              *(u16*)(pbase + wr * 128 + (((ct * 16 + cl) * 2) ^ ((wr & 7) << 4))) = f2bf(e);
            }
        }

        // O += P V ; l += P 1
        const char* VsC = (const char*)Vs;
        #pragma unroll
        for (int ks = 0; ks < 2; ks++){
          const int kvb = ks * 64 + rq * 16;
          bf16x8 pa[2];
          #pragma unroll
          for (int rt = 0; rt < 2; rt++){
            int wr = rt * 16 + cl;
            pa[rt] = *(const bf16x8*)(pbase + wr * 128 + (kvb ^ ((wr & 7) << 4)));
            accl[rt] = __builtin_amdgcn_mfma_f32_16x16x32_bf16(pa[rt], ones, accl[rt], 0, 0, 0);
          }
          #pragma unroll
          for (int n = 0; n < 8; n++){
            int r = n * 16 + cl;
            bf16x8 bfr = *(const bf16x8*)(VsC + r * 128 + (kvb ^ ((r & 7) << 4)));
            #pragma unroll
            for (int rt = 0; rt < 2; rt++)
              acco[rt][n] = __builtin_amdgcn_mfma_f32_16x16x32_bf16(pa[rt], bfr, acco[rt][n], 0, 0, 0);
          }
        }
      }

      __syncthreads();   // Vs + P reads done before next iter's staging
      cur ^= 1;
    }

    if (phx == 0 && nph == 1){
      // A-block: partial seg 0 of long tile
      u16* pO = (u16*)(part + (size_t)((bh * 8 + p) * 2 + 0) * PSTRIDE);
      #pragma unroll
      for (int rt = 0; rt < 2; rt++)
        #pragma unroll
        for (int rr = 0; rr < 4; rr++){
          int prow = wv * 32 + rt * 16 + rq * 4 + rr;
          #pragma unroll
          for (int n = 0; n < 8; n++)
            pO[prow * 128 + n * 16 + cl] = f2bf(acco[rt][n][rr]);
        }
      if (cl == 0){
        float* pm = (float*)((char*)pO + 32768);
        float* pl = (float*)((char*)pO + 33280);
        #pragma unroll
        for (int rt = 0; rt < 2; rt++)
          #pragma unroll
          for (int rr = 0; rr < 4; rr++){
            int prow = wv * 32 + rt * 16 + rq * 4 + rr;
            pm[prow] = mst[rt][rr];
            pl[prow] = accl[rt][rr];
          }
      }
    } else if (phx == 0){
      // B-block phase 0: partial seg 1 of long tile
      u16* pO = (u16*)(part + (size_t)((bh * 8 + p) * 2 + 1) * PSTRIDE);
      #pragma unroll
      for (int rt = 0; rt < 2; rt++)
        #pragma unroll
        for (int rr = 0; rr < 4; rr++){
          int prow = wv * 32 + rt * 16 + rq * 4 + rr;
          #pragma unroll
          for (int n = 0; n < 8; n++)
            pO[prow * 128 + n * 16 + cl] = f2bf(acco[rt][n][rr]);
        }
      if (cl == 0){
        float* pm = (float*)((char*)pO + 32768);
        float* pl = (float*)((char*)pO + 33280);
        #pragma unroll
        for (int rt = 0; rt < 2; rt++)
          #pragma unroll
          for (int rr = 0; rr < 4; rr++){
            int prow = wv * 32 + rt * 16 + rq * 4 + rr;
            pm[prow] = mst[rt][rr];
            pl[prow] = accl[rt][rr];
          }
      }
    } else {
      // B-block phase 1: direct normalized write of short tile
      #pragma unroll
      for (int rt = 0; rt < 2; rt++)
        #pragma unroll
        for (int rr = 0; rr < 4; rr++){
          float inv = 1.0f / accl[rt][rr];
          size_t grow = (size_t)(b * LL + qt1 * 128 + wv * 32 + rt * 16 + rq * 4 + rr);
          #pragma unroll
          for (int n = 0; n < 8; n++)
            aout[grow * HIDD + h * HDD + n * 16 + cl] = f2bf(acco[rt][n][rr] * inv);
        }
    }
  }
}

// combine 2 partials per long tile (qt 8..15) -> aout. grid (8, 32), 256 thr.
__global__ __launch_bounds__(256) void attn_combine_k(
    const char* __restrict__ part, u16* __restrict__ aout)
{
  const int qt = 8 + blockIdx.x, bh = blockIdx.y;
  const int b = bh >> 4, h = bh & 15;
  const int p = 15 - qt;
  const int tid = threadIdx.x;
  const int row = tid >> 1, d0 = (tid & 1) * 64;

  const char* pb0 = part + (size_t)((bh * 8 + p) * 2 + 0) * PSTRIDE;
  const char* pb1 = part + (size_t)((bh * 8 + p) * 2 + 1) * PSTRIDE;
  float m0 = *(const float*)(pb0 + 32768 + row * 4);
  float m1 = *(const float*)(pb1 + 32768 + row * 4);
  float mg = fmaxf(m0, m1);
  float w0 = exp2_fast(m0 - mg);
  float w1 = exp2_fast(m1 - mg);
  float l0 = *(const float*)(pb0 + 33280 + row * 4);
  float l1 = *(const float*)(pb1 + 33280 + row * 4);
  float inv = 1.0f / (w0 * l0 + w1 * l1);
  w0 *= inv; w1 *= inv;

  u16* orow = aout + (size_t)(b * LL + qt * 128 + row) * HIDD + h * HDD + d0;
  for (int c = 0; c < 8; c++){
    bf16x8 v0 = *(const bf16x8*)((const u16*)pb0 + row * 128 + d0 + c * 8);
    bf16x8 v1 = *(const bf16x8*)((const u16*)pb1 + row * 128 + d0 + c * 8);
    ushort4 o0, o1;
    float a0 = w0 * (float)v0[0] + w1 * (float)v1[0];
    float a1 = w0 * (float)v0[1] + w1 * (float)v1[1];
    float a2 = w0 * (float)v0[2] + w1 * (float)v1[2];
    float a3 = w0 * (float)v0[3] + w1 * (float)v1[3];
    float a4 = w0 * (float)v0[4] + w1 * (float)v1[4];
    float a5 = w0 * (float)v0[5] + w1 * (float)v1[5];
    float a6 = w0 * (float)v0[6] + w1 * (float)v1[6];
    float a7 = w0 * (float)v0[7] + w1 * (float)v1[7];
    o0.x = f2bf(a0); o0.y = f2bf(a1); o0.z = f2bf(a2); o0.w = f2bf(a3);
    o1.x = f2bf(a4); o1.y = f2bf(a5); o1.z = f2bf(a6); o1.w = f2bf(a7);
    *(ushort4*)(orow + c * 8)     = o0;
    *(ushort4*)(orow + c * 8 + 4) = o1;
  }
}

// ---------------- launcher ----------------

extern "C" void kernel_launch(void* const* d_in, const int* in_sizes, int n_in,
                              void* d_out, int out_size, void* d_ws, size_t ws_size,
                              hipStream_t stream)
{
  const float* x  = (const float*)d_in[0];
  // d_in[1] = mask (causal; applied analytically)
  const float* Wq = (const float*)d_in[2];
  const float* Wk = (const float*)d_in[3];
  const float* Wv = (const float*)d_in[4];
  const float* Wo = (const float*)d_in[5];
  float* out = (float*)d_out;

  if (ws_size < 134217728ull) return;  // need 128 MB of scratch

  char* ws = (char*)d_ws;
  u16* xb   = (u16*)(ws);                  // 4096x2048 bf16  (16 MB)   dead after gemm1
  u16* Wt   = (u16*)(ws + 16777216ull);    // 6144x2048 bf16  (24 MB)   dead after gemm1
  u16* Wot  = (u16*)(ws + 41943040ull);    // 2048x2048 bf16  ( 8 MB)
  u16* qkv  = (u16*)(ws + 50331648ull);    // 4096x6144 bf16  (48 MB)
  u16* vt   = (u16*)(ws + 100663296ull);   // 32x128x2048 bf16(16 MB)
  u16* aout = (u16*)(ws + 117440512ull);   // 4096x2048 bf16  (16 MB)
  char* part = ws;                          // 32*8*2 x 33KB = 17.3 MB, reuses dead xb region

  cvt_f32_bf16_k<<<2097152 / 256, 256, 0, stream>>>(x, xb, 2097152);
  dim3 tb(32, 8);
  transpose_cvt_k<<<dim3(64, 64), tb, 0, stream>>>(Wq, Wt,                   2048, 2048);
  transpose_cvt_k<<<dim3(64, 64), tb, 0, stream>>>(Wk, Wt + 2048 * 2048,     2048, 2048);
  transpose_cvt_k<<<dim3(64, 64), tb, 0, stream>>>(Wv, Wt + 2 * 2048 * 2048, 2048, 2048);
  transpose_cvt_k<<<dim3(64, 64), tb, 0, stream>>>(Wo, Wot,                  2048, 2048);

  gemm_bt_k<1><<<dim3(6144 / 128, 4096 / 128), 256, 0, stream>>>(xb, Wt, qkv, 4096, 6144, 2048);
  rope_k<<<4194304 / 256, 256, 0, stream>>>(qkv);
  build_vt_k<<<dim3(4, 64, 32), tb, 0, stream>>>(qkv, vt);

  attn_pair_k<<<dim3(32, 16), 256, 0, stream>>>(qkv, vt, aout, part);
  attn_combine_k<<<dim3(8, 32), 256, 0, stream>>>(part, aout);

  gemm_bt_k<0><<<dim3(2048 / 128, 4096 / 128), 256, 0, stream>>>(aout, Wot, out, 4096, 2048, 2048);
}

// Round 11
// 277.268 us; speedup vs baseline: 1.1140x; 1.1140x over previous
//
#include <hip/hip_runtime.h>
#include <math.h>

#define BB   2
#define LL   2048
#define HIDD 2048
#define NHH  16
#define HDD  128
#define QKVN 6144   // 3*HIDD
#define THR2 11.5416f  // defer-max threshold, log2 domain (= 8 nats)

typedef unsigned short u16;
typedef float  f32x4 __attribute__((ext_vector_type(4)));
typedef __bf16 bf16x8 __attribute__((ext_vector_type(8)));

static __device__ __forceinline__ float exp2_fast(float x){
  return __builtin_amdgcn_exp2f(x);    // v_exp_f32 (native 2^x)
}
static __device__ __forceinline__ u16 f2bf(float x){
  unsigned u = __float_as_uint(x);
  return (u16)((u + 0x7fffu + ((u >> 16) & 1u)) >> 16);
}
static __device__ __forceinline__ float bf2f(u16 b){
  return __uint_as_float(((unsigned)b) << 16);
}
static __device__ __forceinline__ void gl_lds16(const void* g, void* l){
  __builtin_amdgcn_global_load_lds(
      (__attribute__((address_space(1))) void*)(void*)g,
      (__attribute__((address_space(3))) void*)l,
      16, 0, 0);
}

// ---------------- prep kernels ----------------

__global__ void cvt_f32_bf16_k(const float* __restrict__ src, u16* __restrict__ dst, int n4){
  int i = blockIdx.x * blockDim.x + threadIdx.x;
  if (i >= n4) return;
  float4 v = ((const float4*)src)[i];
  ushort4 o;
  o.x = f2bf(v.x); o.y = f2bf(v.y); o.z = f2bf(v.z); o.w = f2bf(v.w);
  ((ushort4*)dst)[i] = o;
}

// fused 4x (2048^2 f32 -> transposed bf16). grid (32,32,4), 256 thr, 64x64 tiles.
// loads float4 coalesced; stores bf16x8 (16B lines). LDS u16[64][66] (bank-spread);
// reads via 4 aligned u32s per store.
__global__ __launch_bounds__(256) void transpose_cvt4_k(
    const float* __restrict__ Wq, const float* __restrict__ Wk,
    const float* __restrict__ Wv, const float* __restrict__ Wo,
    u16* __restrict__ Wt, u16* __restrict__ Wot)
{
  __shared__ u16 t[64][66];
  const int z = blockIdx.z;
  const float* src = (z == 0) ? Wq : (z == 1) ? Wk : (z == 2) ? Wv : Wo;
  u16* dst = (z == 3) ? Wot : (Wt + (size_t)z * 2048 * 2048);
  const int c0 = blockIdx.x * 64, r0 = blockIdx.y * 64;
  const int tid = threadIdx.x;

  #pragma unroll
  for (int i = 0; i < 4; i++){
    int r  = i * 16 + (tid >> 4);
    int c4 = (tid & 15) * 4;
    float4 v = *(const float4*)&src[(size_t)(r0 + r) * 2048 + c0 + c4];
    t[c4 + 0][r] = f2bf(v.x);
    t[c4 + 1][r] = f2bf(v.y);
    t[c4 + 2][r] = f2bf(v.z);
    t[c4 + 3][r] = f2bf(v.w);
  }
  __syncthreads();
  #pragma unroll
  for (int i = 0; i < 2; i++){
    int c  = i * 32 + (tid >> 3);
    int rs = (tid & 7) * 8;
    const unsigned* p = (const unsigned*)&t[c][rs];   // 4B-aligned (132c+16k)
    unsigned w0 = p[0], w1 = p[1], w2 = p[2], w3 = p[3];
    u16* d = &dst[(size_t)(c0 + c) * 2048 + r0 + rs];
    ((unsigned*)d)[0] = w0; ((unsigned*)d)[1] = w1;
    ((unsigned*)d)[2] = w2; ((unsigned*)d)[3] = w3;
  }
}

// in-place RoPE on q,k sections of qkv (bf16). idx over B*L*NH*64
// Q additionally pre-scaled by 1/sqrt(128)*log2(e) -> scores in exp2 domain.
__global__ void rope_k(u16* __restrict__ qkv){
  int idx = blockIdx.x * blockDim.x + threadIdx.x;
  int d   = idx & 63;
  int h   = (idx >> 6) & 15;
  int row = idx >> 10;           // b*L + l
  int l   = row & (LL - 1);
  float fr = __expf(-(float)d * 0.17988946f);   // ln(1e5)/64
  float th = (float)l * 0.25f * fr;             // pos/ROPE_SCALE * freq
  float s, c;
  sincosf(th, &s, &c);
  size_t base = (size_t)row * QKVN + h * HDD + d;
  #pragma unroll
  for (int part = 0; part < 2; part++){         // q then k
    float f = (part == 0) ? 0.12753375f : 1.0f; // scale*log2e folded into Q
    float x1 = bf2f(qkv[base]), x2 = bf2f(qkv[base + 64]);
    qkv[base]      = f2bf((x1 * c - x2 * s) * f);
    qkv[base + 64] = f2bf((x1 * s + x2 * c) * f);
    base += HIDD;
  }
}

// v section of qkv -> vt[(b,h), d, l]
__global__ void build_vt_k(const u16* __restrict__ qkv, u16* __restrict__ vt){
  __shared__ u16 t[32][33];
  int bh = blockIdx.z;
  int b = bh >> 4, h = bh & 15;
  const u16* src = qkv + (size_t)b * LL * QKVN + 2 * HIDD + h * HDD; // [l][d] stride QKVN
  u16* dst = vt + (size_t)bh * HDD * LL;                              // [d][l] stride LL
  int d0 = blockIdx.x * 32, l0 = blockIdx.y * 32;
  int tx = threadIdx.x, ty = threadIdx.y;
  #pragma unroll
  for (int i = 0; i < 32; i += 8) t[ty + i][tx] = src[(size_t)(l0 + ty + i) * QKVN + d0 + tx];
  __syncthreads();
  #pragma unroll
  for (int i = 0; i < 32; i += 8) dst[(size_t)(d0 + ty + i) * LL + l0 + tx] = t[tx][ty + i];
}

// ---------------- GEMM 128x128 (proven for gemm1): C = A * Bt^T ----------------

template<int OUT_BF16>
__global__ __launch_bounds__(256) void gemm_bt_k(
    const u16* __restrict__ A, const u16* __restrict__ Bt,
    void* __restrict__ Cout, int M, int N, int K)
{
  __shared__ __align__(16) u16 As[128 * 64];
  __shared__ __align__(16) u16 Bs[128 * 64];
  const int tid = threadIdx.x, lane = tid & 63, wv = tid >> 6;
  const int wr = wv >> 1, wc = wv & 1;
  const int m0 = blockIdx.y * 128, n0 = blockIdx.x * 128;
  const int rq = lane >> 4, cl = lane & 15;

  const f32x4 Z = {0.f, 0.f, 0.f, 0.f};
  f32x4 acc[4][4];
  #pragma unroll
  for (int m = 0; m < 4; m++)
    #pragma unroll
    for (int n = 0; n < 4; n++) acc[m][n] = Z;

  for (int kt = 0; kt < K; kt += 64){
    #pragma unroll
    for (int i = 0; i < 4; i++){
      int fb = (i * 4 + wv) * 64;          // wave-uniform 16B-chunk base
      int p  = (fb + lane) * 16;           // this lane's physical LDS byte
      int r  = p >> 7;                     // tile row (128B rows)
      int cbs = (p & 127) ^ ((r & 7) << 4);
      gl_lds16(A  + (size_t)(m0 + r) * K + kt + (cbs >> 1), &As[fb * 8]);
      gl_lds16(Bt + (size_t)(n0 + r) * K + kt + (cbs >> 1), &Bs[fb * 8]);
    }
    __syncthreads();
    #pragma unroll
    for (int ks = 0; ks < 2; ks++){
      const int kb = ks * 64 + rq * 16;    // k byte offset in row
      bf16x8 a[4], b[4];
      #pragma unroll
      for (int m = 0; m < 4; m++){
        int r = wr * 64 + m * 16 + cl;
        a[m] = *(const bf16x8*)((const char*)As + r * 128 + (kb ^ ((r & 7) << 4)));
      }
      #pragma unroll
      for (int n = 0; n < 4; n++){
        int r = wc * 64 + n * 16 + cl;
        b[n] = *(const bf16x8*)((const char*)Bs + r * 128 + (kb ^ ((r & 7) << 4)));
      }
      #pragma unroll
      for (int m = 0; m < 4; m++)
        #pragma unroll
        for (int n = 0; n < 4; n++)
          acc[m][n] = __builtin_amdgcn_mfma_f32_16x16x32_bf16(a[m], b[n], acc[m][n], 0, 0, 0);
    }
    __syncthreads();
  }

  #pragma unroll
  for (int m = 0; m < 4; m++){
    int gr0 = m0 + wr * 64 + m * 16 + rq * 4;
    #pragma unroll
    for (int n = 0; n < 4; n++){
      int gc = n0 + wc * 64 + n * 16 + cl;
      #pragma unroll
      for (int rr = 0; rr < 4; rr++){
        if (OUT_BF16) ((u16*)Cout)[(size_t)(gr0 + rr) * N + gc] = f2bf(acc[m][n][rr]);
        else          ((float*)Cout)[(size_t)(gr0 + rr) * N + gc] = acc[m][n][rr];
      }
    }
  }
}

// ---------------- GEMM 128x256 counted-vmcnt (proven for gemm2) ----------------

#define G2_STAGE(kt, bsel) do {                                                           \
  _Pragma("unroll")                                                                       \
  for (int i_ = 0; i_ < 2; i_++){     /* A: 128x64 = 1024 chunks */                       \
    int c_ = ((i_ * 8 + wv) * 64) + lane;                                                 \
    int p_ = c_ * 16;                                                                     \
    int r_ = p_ >> 7; int cb_ = (p_ & 127) ^ ((r_ & 7) << 4);                             \
    gl_lds16(A + (size_t)(m0 + r_) * K + (kt) + (cb_ >> 1),                               \
             &AB[bsel][((i_ * 8 + wv) * 64) * 8]);                                        \
  }                                                                                       \
  _Pragma("unroll")                                                                       \
  for (int i_ = 0; i_ < 4; i_++){     /* B: 256x64 = 2048 chunks */                       \
    int c_ = ((i_ * 8 + wv) * 64) + lane;                                                 \
    int p_ = c_ * 16;                                                                     \
    int r_ = p_ >> 7; int cb_ = (p_ & 127) ^ ((r_ & 7) << 4);                             \
    gl_lds16(Bt + (size_t)(n0 + r_) * K + (kt) + (cb_ >> 1),                              \
             &AB[bsel][8192 + ((i_ * 8 + wv) * 64) * 8]);                                 \
  }                                                                                       \
} while(0)

template<int OUT_BF16>
__global__ __launch_bounds__(512, 1) void gemm_bt2_k(
    const u16* __restrict__ A, const u16* __restrict__ Bt,
    void* __restrict__ Cout, int M, int N, int K)
{
  __shared__ __align__(16) u16 AB[2][24576];   // per buf: A[128][64] @0, B[256][64] @8192
  const int tid = threadIdx.x, lane = tid & 63, wv = tid >> 6;
  const int wr = wv >> 2, wc = wv & 3;          // 2 (M) x 4 (N) waves
  const int m0 = blockIdx.y * 128, n0 = blockIdx.x * 256;
  const int rq = lane >> 4, cl = lane & 15;
  const int NT = K >> 6;                        // 64-wide K tiles

  const f32x4 Z = {0.f, 0.f, 0.f, 0.f};
  f32x4 acc[4][4];
  #pragma unroll
  for (int m = 0; m < 4; m++)
    #pragma unroll
    for (int n = 0; n < 4; n++) acc[m][n] = Z;

  // prologue: stage tiles 0 and 1; wait only for tile 0 (6 loads of tile 1 in flight)
  G2_STAGE(0, 0);
  G2_STAGE(64, 1);
  asm volatile("s_waitcnt vmcnt(6)");
  __builtin_amdgcn_sched_barrier(0);
  __builtin_amdgcn_s_barrier();

  int cur = 0;
  for (int t = 0; t < NT; t++){
    const char* As_ = (const char*)&AB[cur][0];
    const char* Bs_ = (const char*)&AB[cur][8192];

    #pragma unroll
    for (int ks = 0; ks < 2; ks++){
      const int kb = ks * 64 + rq * 16;
      bf16x8 a[4], b[4];
      #pragma unroll
      for (int m = 0; m < 4; m++){
        int r = wr * 64 + m * 16 + cl;
        a[m] = *(const bf16x8*)(As_ + r * 128 + (kb ^ ((r & 7) << 4)));
      }
      #pragma unroll
      for (int n = 0; n < 4; n++){
        int r = wc * 64 + n * 16 + cl;
        b[n] = *(const bf16x8*)(Bs_ + r * 128 + (kb ^ ((r & 7) << 4)));
      }
      __builtin_amdgcn_s_setprio(1);
      #pragma unroll
      for (int m = 0; m < 4; m++)
        #pragma unroll
        for (int n = 0; n < 4; n++)
          acc[m][n] = __builtin_amdgcn_mfma_f32_16x16x32_bf16(a[m], b[n], acc[m][n], 0, 0, 0);
      __builtin_amdgcn_s_setprio(0);
    }

    __builtin_amdgcn_sched_barrier(0);
    __builtin_amdgcn_s_barrier();              // every wave done READING buf[cur]

    if (t + 2 < NT){
      G2_STAGE((t + 2) * 64, cur);             // overwrite freed buffer
      asm volatile("s_waitcnt vmcnt(6)");      // tile t+1 landed; t+2 stays in flight
    } else {
      asm volatile("s_waitcnt vmcnt(0)");      // tail: drain remaining
    }
    __builtin_amdgcn_sched_barrier(0);
    __builtin_amdgcn_s_barrier();              // every wave's tile t+1 landed
    cur ^= 1;
  }

  #pragma unroll
  for (int m = 0; m < 4; m++){
    int gr0 = m0 + wr * 64 + m * 16 + rq * 4;
    #pragma unroll
    for (int n = 0; n < 4; n++){
      int gc = n0 + wc * 64 + n * 16 + cl;
      #pragma unroll
      for (int rr = 0; rr < 4; rr++){
        if (OUT_BF16) ((u16*)Cout)[(size_t)(gr0 + rr) * N + gc] = f2bf(acc[m][n][rr]);
        else          ((float*)Cout)[(size_t)(gr0 + rr) * N + gc] = acc[m][n][rr];
      }
    }
  }
}

// ---------------- flash attention: paired q-tiles, uniform blocks (r6-proven) ----------
// grid (bh=32 fast, pair p=0..7), 512 threads = 8 waves x 16 q-rows.
// Block processes q-tile (15-p) then q-tile p: exactly 34 tile-iters per block.
// K double-buffered, V single-buffered, P overlays the consumed K buffer.

#define STAGE_K(jj, bsel) do {                                                            \
  _Pragma("unroll")                                                                       \
  for (int i_ = 0; i_ < 2; i_++){                                                         \
    int fb_ = (i_ * 8 + wv) * 64;                                                         \
    int p_  = (fb_ + lane) * 16;                                                          \
    int r_ = p_ >> 8; int cb_ = (p_ & 255) ^ ((r_ & 7) << 4);                             \
    gl_lds16(qkv + (size_t)(b * LL + (jj) * 64 + r_) * QKVN + HIDD + h * HDD + (cb_ >> 1),\
             &Kb[bsel][fb_ * 8]);                                                         \
  }                                                                                       \
} while(0)

#define STAGE_V(jj) do {                                                                  \
  _Pragma("unroll")                                                                       \
  for (int i_ = 0; i_ < 2; i_++){                                                         \
    int fb_ = (i_ * 8 + wv) * 64;                                                         \
    int p_  = (fb_ + lane) * 16;                                                          \
    int r_ = p_ >> 7; int cb_ = (p_ & 127) ^ ((r_ & 7) << 4);                             \
    gl_lds16(vt + (size_t)(bh * HDD + r_) * LL + (jj) * 64 + (cb_ >> 1), &Vs[fb_ * 8]);   \
  }                                                                                       \
} while(0)

__global__ __launch_bounds__(512, 1) void attn_k(
    const u16* __restrict__ qkv, const u16* __restrict__ vt,
    u16* __restrict__ aout)
{
  __shared__ __align__(16) u16 Kb[2][64 * 128];   // K tiles [64][128], 2x16KB
  __shared__ __align__(16) u16 Vs[128 * 64];      // V^T tile [128][64], 16KB
  const int tid = threadIdx.x, lane = tid & 63, wv = tid >> 6;
  const int bh = blockIdx.x;                      // fast dim -> XCD = bh % 8
  const int pr = blockIdx.y;                      // pair index 0..7
  const int b = bh >> 4, h = bh & 15;
  const int rq = lane >> 4, cl = lane & 15;

  bf16x8 ones;
  #pragma unroll
  for (int i = 0; i < 8; i++) ones[i] = (__bf16)1.0f;
  const f32x4 Z = {0.f, 0.f, 0.f, 0.f};

  int cur = 0;
  STAGE_K(0, 0);                                  // phase-A tile 0

  #pragma unroll
  for (int ph = 0; ph < 2; ph++){
    const int qt = ph ? pr : (15 - pr);
    const int nj = 2 * qt + 2;

    // Q fragments for this q-tile: wave rows qt*128 + wv*16 + cl
    bf16x8 qf[4];
    {
      const u16* qb = qkv + (size_t)(b * LL + qt * 128 + wv * 16 + cl) * QKVN + h * HDD + rq * 8;
      #pragma unroll
      for (int ks = 0; ks < 4; ks++) qf[ks] = *(const bf16x8*)(qb + ks * 32);
    }

    f32x4 acco[8], accl;
    float mst[4];
    #pragma unroll
    for (int n = 0; n < 8; n++) acco[n] = Z;
    accl = Z;
    #pragma unroll
    for (int rr = 0; rr < 4; rr++) mst[rr] = -INFINITY;

    const int wrow_hi = qt * 128 + wv * 16 + 15;

    if (ph == 0) __syncthreads();                 // initial K landed

    for (int j = 0; j < nj; j++){
      // prefetch next K tile (crosses the phase boundary into phase B's j=0)
      if (j + 1 < nj)      STAGE_K(j + 1, cur ^ 1);
      else if (ph == 0)    STAGE_K(0,     cur ^ 1);
      STAGE_V(j);
      const bool act = (j * 64 <= wrow_hi);

      f32x4 sv[4];
      if (act){
        const char* KsC = (const char*)&Kb[cur][0];
        #pragma unroll
        for (int ct = 0; ct < 4; ct++) sv[ct] = Z;
        #pragma unroll
        for (int ks = 0; ks < 4; ks++){
          const int kb = ks * 64 + rq * 16;
          #pragma unroll
          for (int ct = 0; ct < 4; ct++){
            int r = ct * 16 + cl;
            bf16x8 bfr = *(const bf16x8*)(KsC + r * 256 + (kb ^ ((r & 7) << 4)));
            sv[ct] = __builtin_amdgcn_mfma_f32_16x16x32_bf16(qf[ks], bfr, sv[ct], 0, 0, 0);
          }
        }
      }

      __syncthreads();   // QK reads of Kb[cur] done; V (and next K) landed

      if (act){
        char* pbase = (char*)&Kb[cur][0] + wv * 2048;   // P overlays consumed K
        const bool msk = (j >= 2 * qt);

        float p4[4][4], lmx[4];
        #pragma unroll
        for (int rr = 0; rr < 4; rr++) lmx[rr] = -1e30f;
        const int qg = qt * 128 + wv * 16 + rq * 4;
        #pragma unroll
        for (int ct = 0; ct < 4; ct++){
          int col = j * 64 + ct * 16 + cl;
          #pragma unroll
          for (int rr = 0; rr < 4; rr++){
            float v = sv[ct][rr];                 // already log2-domain
            if (msk && col > qg + rr) v = -1e30f;
            p4[ct][rr] = v;
            lmx[rr] = fmaxf(lmx[rr], v);
          }
        }
        // defer-max gate
        float need = -1e30f;
        #pragma unroll
        for (int rr = 0; rr < 4; rr++) need = fmaxf(need, lmx[rr] - mst[rr]);
        if (__any(need > THR2)){
          float mx[4];
          #pragma unroll
          for (int rr = 0; rr < 4; rr++) mx[rr] = lmx[rr];
          #pragma unroll
          for (int off = 1; off < 16; off <<= 1)
            #pragma unroll
            for (int rr = 0; rr < 4; rr++)
              mx[rr] = fmaxf(mx[rr], __shfl_xor(mx[rr], off, 64));
          #pragma unroll
          for (int rr = 0; rr < 4; rr++){
            float mn  = fmaxf(mst[rr], mx[rr]);
            float fsc = exp2_fast(mst[rr] - mn);
            mst[rr] = mn;
            accl[rr] *= fsc;
            #pragma unroll
            for (int n = 0; n < 8; n++) acco[n][rr] *= fsc;
          }
        }
        #pragma unroll
        for (int ct = 0; ct < 4; ct++)
          #pragma unroll
          for (int rr = 0; rr < 4; rr++){
            float e = exp2_fast(p4[ct][rr] - mst[rr]);
            int wr = rq * 4 + rr;
            *(u16*)(pbase + wr * 128 + (((ct * 16 + cl) * 2) ^ ((wr & 7) << 4))) = f2bf(e);
          }

        // O += P V ; l += P 1
        const char* VsC = (const char*)Vs;
        #pragma unroll
        for (int ks = 0; ks < 2; ks++){
          const int kvb = ks * 64 + rq * 16;
          bf16x8 pa = *(const bf16x8*)(pbase + cl * 128 + (kvb ^ ((cl & 7) << 4)));
          accl = __builtin_amdgcn_mfma_f32_16x16x32_bf16(pa, ones, accl, 0, 0, 0);
          #pragma unroll
          for (int n = 0; n < 8; n++){
            int r = n * 16 + cl;
            bf16x8 bfr = *(const bf16x8*)(VsC + r * 128 + (kvb ^ ((r & 7) << 4)));
            acco[n] = __builtin_amdgcn_mfma_f32_16x16x32_bf16(pa, bfr, acco[n], 0, 0, 0);
          }
        }
      }

      __syncthreads();   // Vs + P reads done before next iter's staging
      cur ^= 1;
    }

    // direct write-out
    #pragma unroll
    for (int rr = 0; rr < 4; rr++){
      float inv = 1.0f / accl[rr];
      size_t grow = (size_t)(b * LL + qt * 128 + wv * 16 + rq * 4 + rr);
      #pragma unroll
      for (int n = 0; n < 8; n++)
        aout[grow * HIDD + h * HDD + n * 16 + cl] = f2bf(acco[n][rr] * inv);
    }
  }
}

// ---------------- launcher ----------------

extern "C" void kernel_launch(void* const* d_in, const int* in_sizes, int n_in,
                              void* d_out, int out_size, void* d_ws, size_t ws_size,
                              hipStream_t stream)
{
  const float* x  = (const float*)d_in[0];
  // d_in[1] = mask (causal; applied analytically)
  const float* Wq = (const float*)d_in[2];
  const float* Wk = (const float*)d_in[3];
  const float* Wv = (const float*)d_in[4];
  const float* Wo = (const float*)d_in[5];
  float* out = (float*)d_out;

  if (ws_size < 134217728ull) return;  // need 128 MB of scratch

  char* ws = (char*)d_ws;
  u16* xb   = (u16*)(ws);                  // 4096x2048 bf16  (16 MB)
  u16* Wt   = (u16*)(ws + 16777216ull);    // 6144x2048 bf16  (24 MB) = [Wq|Wk|Wv]^T
  u16* Wot  = (u16*)(ws + 41943040ull);    // 2048x2048 bf16  ( 8 MB)
  u16* qkv  = (u16*)(ws + 50331648ull);    // 4096x6144 bf16  (48 MB)
  u16* vt   = (u16*)(ws + 100663296ull);   // 32x128x2048 bf16(16 MB)
  u16* aout = (u16*)(ws + 117440512ull);   // 4096x2048 bf16  (16 MB)

  cvt_f32_bf16_k<<<2097152 / 256, 256, 0, stream>>>(x, xb, 2097152);
  transpose_cvt4_k<<<dim3(32, 32, 4), 256, 0, stream>>>(Wq, Wk, Wv, Wo, Wt, Wot);

  gemm_bt_k<1><<<dim3(6144 / 128, 4096 / 128), 256, 0, stream>>>(xb, Wt, qkv, 4096, 6144, 2048);
  rope_k<<<4194304 / 256, 256, 0, stream>>>(qkv);
  build_vt_k<<<dim3(4, 64, 32), dim3(32, 8), 0, stream>>>(qkv, vt);

  attn_k<<<dim3(32, 8), 512, 0, stream>>>(qkv, vt, aout);

  gemm_bt2_k<0><<<dim3(2048 / 256, 4096 / 128), 512, 0, stream>>>(aout, Wot, out, 4096, 2048, 2048);
}

// Round 12
// 268.921 us; speedup vs baseline: 1.1486x; 1.0310x over previous
//
#include <hip/hip_runtime.h>
#include <math.h>

#define BB   2
#define LL   2048
#define HIDD 2048
#define NHH  16
#define HDD  128
#define QKVN 6144   // 3*HIDD
#define THR2 11.5416f  // defer-max threshold, log2 domain (= 8 nats)

typedef unsigned short u16;
typedef float  f32x4 __attribute__((ext_vector_type(4)));
typedef __bf16 bf16x8 __attribute__((ext_vector_type(8)));

static __device__ __forceinline__ float exp2_fast(float x){
  return __builtin_amdgcn_exp2f(x);    // v_exp_f32 (native 2^x)
}
static __device__ __forceinline__ u16 f2bf(float x){
  unsigned u = __float_as_uint(x);
  return (u16)((u + 0x7fffu + ((u >> 16) & 1u)) >> 16);
}
static __device__ __forceinline__ float bf2f(u16 b){
  return __uint_as_float(((unsigned)b) << 16);
}
static __device__ __forceinline__ void gl_lds16(const void* g, void* l){
  __builtin_amdgcn_global_load_lds(
      (__attribute__((address_space(1))) void*)(void*)g,
      (__attribute__((address_space(3))) void*)l,
      16, 0, 0);
}

// ---------------- prep kernels ----------------

__global__ void cvt_f32_bf16_k(const float* __restrict__ src, u16* __restrict__ dst, int n4){
  int i = blockIdx.x * blockDim.x + threadIdx.x;
  if (i >= n4) return;
  float4 v = ((const float4*)src)[i];
  ushort4 o;
  o.x = f2bf(v.x); o.y = f2bf(v.y); o.z = f2bf(v.z); o.w = f2bf(v.w);
  ((ushort4*)dst)[i] = o;
}

// fused 4x (2048^2 f32 -> transposed bf16). grid (32,32,4), 256 thr, 64x64 tiles.
__global__ __launch_bounds__(256) void transpose_cvt4_k(
    const float* __restrict__ Wq, const float* __restrict__ Wk,
    const float* __restrict__ Wv, const float* __restrict__ Wo,
    u16* __restrict__ Wt, u16* __restrict__ Wot)
{
  __shared__ u16 t[64][66];
  const int z = blockIdx.z;
  const float* src = (z == 0) ? Wq : (z == 1) ? Wk : (z == 2) ? Wv : Wo;
  u16* dst = (z == 3) ? Wot : (Wt + (size_t)z * 2048 * 2048);
  const int c0 = blockIdx.x * 64, r0 = blockIdx.y * 64;
  const int tid = threadIdx.x;

  #pragma unroll
  for (int i = 0; i < 4; i++){
    int r  = i * 16 + (tid >> 4);
    int c4 = (tid & 15) * 4;
    float4 v = *(const float4*)&src[(size_t)(r0 + r) * 2048 + c0 + c4];
    t[c4 + 0][r] = f2bf(v.x);
    t[c4 + 1][r] = f2bf(v.y);
    t[c4 + 2][r] = f2bf(v.z);
    t[c4 + 3][r] = f2bf(v.w);
  }
  __syncthreads();
  #pragma unroll
  for (int i = 0; i < 2; i++){
    int c  = i * 32 + (tid >> 3);
    int rs = (tid & 7) * 8;
    const unsigned* p = (const unsigned*)&t[c][rs];   // 4B-aligned
    unsigned w0 = p[0], w1 = p[1], w2 = p[2], w3 = p[3];
    u16* d = &dst[(size_t)(c0 + c) * 2048 + r0 + rs];
    ((unsigned*)d)[0] = w0; ((unsigned*)d)[1] = w1;
    ((unsigned*)d)[2] = w2; ((unsigned*)d)[3] = w3;
  }
}

// in-place RoPE on q,k sections of qkv (bf16). idx over B*L*NH*64
// Q additionally pre-scaled by 1/sqrt(128)*log2(e) -> scores in exp2 domain.
__global__ void rope_k(u16* __restrict__ qkv){
  int idx = blockIdx.x * blockDim.x + threadIdx.x;
  int d   = idx & 63;
  int h   = (idx >> 6) & 15;
  int row = idx >> 10;           // b*L + l
  int l   = row & (LL - 1);
  float fr = __expf(-(float)d * 0.17988946f);   // ln(1e5)/64
  float th = (float)l * 0.25f * fr;             // pos/ROPE_SCALE * freq
  float s, c;
  sincosf(th, &s, &c);
  size_t base = (size_t)row * QKVN + h * HDD + d;
  #pragma unroll
  for (int part = 0; part < 2; part++){         // q then k
    float f = (part == 0) ? 0.12753375f : 1.0f; // scale*log2e folded into Q
    float x1 = bf2f(qkv[base]), x2 = bf2f(qkv[base + 64]);
    qkv[base]      = f2bf((x1 * c - x2 * s) * f);
    qkv[base + 64] = f2bf((x1 * s + x2 * c) * f);
    base += HIDD;
  }
}

// v section of qkv -> vt[(b,h), d, l]
__global__ void build_vt_k(const u16* __restrict__ qkv, u16* __restrict__ vt){
  __shared__ u16 t[32][33];
  int bh = blockIdx.z;
  int b = bh >> 4, h = bh & 15;
  const u16* src = qkv + (size_t)b * LL * QKVN + 2 * HIDD + h * HDD; // [l][d] stride QKVN
  u16* dst = vt + (size_t)bh * HDD * LL;                              // [d][l] stride LL
  int d0 = blockIdx.x * 32, l0 = blockIdx.y * 32;
  int tx = threadIdx.x, ty = threadIdx.y;
  #pragma unroll
  for (int i = 0; i < 32; i += 8) t[ty + i][tx] = src[(size_t)(l0 + ty + i) * QKVN + d0 + tx];
  __syncthreads();
  #pragma unroll
  for (int i = 0; i < 32; i += 8) dst[(size_t)(d0 + ty + i) * LL + l0 + tx] = t[tx][ty + i];
}

// ---------------- GEMM 128x128 (proven for gemm1): C = A * Bt^T ----------------

template<int OUT_BF16>
__global__ __launch_bounds__(256) void gemm_bt_k(
    const u16* __restrict__ A, const u16* __restrict__ Bt,
    void* __restrict__ Cout, int M, int N, int K)
{
  __shared__ __align__(16) u16 As[128 * 64];
  __shared__ __align__(16) u16 Bs[128 * 64];
  const int tid = threadIdx.x, lane = tid & 63, wv = tid >> 6;
  const int wr = wv >> 1, wc = wv & 1;
  const int m0 = blockIdx.y * 128, n0 = blockIdx.x * 128;
  const int rq = lane >> 4, cl = lane & 15;

  const f32x4 Z = {0.f, 0.f, 0.f, 0.f};
  f32x4 acc[4][4];
  #pragma unroll
  for (int m = 0; m < 4; m++)
    #pragma unroll
    for (int n = 0; n < 4; n++) acc[m][n] = Z;

  for (int kt = 0; kt < K; kt += 64){
    #pragma unroll
    for (int i = 0; i < 4; i++){
      int fb = (i * 4 + wv) * 64;          // wave-uniform 16B-chunk base
      int p  = (fb + lane) * 16;           // this lane's physical LDS byte
      int r  = p >> 7;                     // tile row (128B rows)
      int cbs = (p & 127) ^ ((r & 7) << 4);
      gl_lds16(A  + (size_t)(m0 + r) * K + kt + (cbs >> 1), &As[fb * 8]);
      gl_lds16(Bt + (size_t)(n0 + r) * K + kt + (cbs >> 1), &Bs[fb * 8]);
    }
    __syncthreads();
    #pragma unroll
    for (int ks = 0; ks < 2; ks++){
      const int kb = ks * 64 + rq * 16;    // k byte offset in row
      bf16x8 a[4], b[4];
      #pragma unroll
      for (int m = 0; m < 4; m++){
        int r = wr * 64 + m * 16 + cl;
        a[m] = *(const bf16x8*)((const char*)As + r * 128 + (kb ^ ((r & 7) << 4)));
      }
      #pragma unroll
      for (int n = 0; n < 4; n++){
        int r = wc * 64 + n * 16 + cl;
        b[n] = *(const bf16x8*)((const char*)Bs + r * 128 + (kb ^ ((r & 7) << 4)));
      }
      #pragma unroll
      for (int m = 0; m < 4; m++)
        #pragma unroll
        for (int n = 0; n < 4; n++)
          acc[m][n] = __builtin_amdgcn_mfma_f32_16x16x32_bf16(a[m], b[n], acc[m][n], 0, 0, 0);
    }
    __syncthreads();
  }

  #pragma unroll
  for (int m = 0; m < 4; m++){
    int gr0 = m0 + wr * 64 + m * 16 + rq * 4;
    #pragma unroll
    for (int n = 0; n < 4; n++){
      int gc = n0 + wc * 64 + n * 16 + cl;
      #pragma unroll
      for (int rr = 0; rr < 4; rr++){
        if (OUT_BF16) ((u16*)Cout)[(size_t)(gr0 + rr) * N + gc] = f2bf(acc[m][n][rr]);
        else          ((float*)Cout)[(size_t)(gr0 + rr) * N + gc] = acc[m][n][rr];
      }
    }
  }
}

// ---------------- GEMM 128x256 counted-vmcnt (proven for gemm2) ----------------

#define G2_STAGE(kt, bsel) do {                                                           \
  _Pragma("unroll")                                                                       \
  for (int i_ = 0; i_ < 2; i_++){     /* A: 128x64 = 1024 chunks */                       \
    int c_ = ((i_ * 8 + wv) * 64) + lane;                                                 \
    int p_ = c_ * 16;                                                                     \
    int r_ = p_ >> 7; int cb_ = (p_ & 127) ^ ((r_ & 7) << 4);                             \
    gl_lds16(A + (size_t)(m0 + r_) * K + (kt) + (cb_ >> 1),                               \
             &AB[bsel][((i_ * 8 + wv) * 64) * 8]);                                        \
  }                                                                                       \
  _Pragma("unroll")                                                                       \
  for (int i_ = 0; i_ < 4; i_++){     /* B: 256x64 = 2048 chunks */                       \
    int c_ = ((i_ * 8 + wv) * 64) + lane;                                                 \
    int p_ = c_ * 16;                                                                     \
    int r_ = p_ >> 7; int cb_ = (p_ & 127) ^ ((r_ & 7) << 4);                             \
    gl_lds16(Bt + (size_t)(n0 + r_) * K + (kt) + (cb_ >> 1),                              \
             &AB[bsel][8192 + ((i_ * 8 + wv) * 64) * 8]);                                 \
  }                                                                                       \
} while(0)

template<int OUT_BF16>
__global__ __launch_bounds__(512, 1) void gemm_bt2_k(
    const u16* __restrict__ A, const u16* __restrict__ Bt,
    void* __restrict__ Cout, int M, int N, int K)
{
  __shared__ __align__(16) u16 AB[2][24576];   // per buf: A[128][64] @0, B[256][64] @8192
  const int tid = threadIdx.x, lane = tid & 63, wv = tid >> 6;
  const int wr = wv >> 2, wc = wv & 3;          // 2 (M) x 4 (N) waves
  const int m0 = blockIdx.y * 128, n0 = blockIdx.x * 256;
  const int rq = lane >> 4, cl = lane & 15;
  const int NT = K >> 6;                        // 64-wide K tiles

  const f32x4 Z = {0.f, 0.f, 0.f, 0.f};
  f32x4 acc[4][4];
  #pragma unroll
  for (int m = 0; m < 4; m++)
    #pragma unroll
    for (int n = 0; n < 4; n++) acc[m][n] = Z;

  G2_STAGE(0, 0);
  G2_STAGE(64, 1);
  asm volatile("s_waitcnt vmcnt(6)");
  __builtin_amdgcn_sched_barrier(0);
  __builtin_amdgcn_s_barrier();

  int cur = 0;
  for (int t = 0; t < NT; t++){
    const char* As_ = (const char*)&AB[cur][0];
    const char* Bs_ = (const char*)&AB[cur][8192];

    #pragma unroll
    for (int ks = 0; ks < 2; ks++){
      const int kb = ks * 64 + rq * 16;
      bf16x8 a[4], b[4];
      #pragma unroll
      for (int m = 0; m < 4; m++){
        int r = wr * 64 + m * 16 + cl;
        a[m] = *(const bf16x8*)(As_ + r * 128 + (kb ^ ((r & 7) << 4)));
      }
      #pragma unroll
      for (int n = 0; n < 4; n++){
        int r = wc * 64 + n * 16 + cl;
        b[n] = *(const bf16x8*)(Bs_ + r * 128 + (kb ^ ((r & 7) << 4)));
      }
      __builtin_amdgcn_s_setprio(1);
      #pragma unroll
      for (int m = 0; m < 4; m++)
        #pragma unroll
        for (int n = 0; n < 4; n++)
          acc[m][n] = __builtin_amdgcn_mfma_f32_16x16x32_bf16(a[m], b[n], acc[m][n], 0, 0, 0);
      __builtin_amdgcn_s_setprio(0);
    }

    __builtin_amdgcn_sched_barrier(0);
    __builtin_amdgcn_s_barrier();              // every wave done READING buf[cur]

    if (t + 2 < NT){
      G2_STAGE((t + 2) * 64, cur);             // overwrite freed buffer
      asm volatile("s_waitcnt vmcnt(6)");      // tile t+1 landed; t+2 stays in flight
    } else {
      asm volatile("s_waitcnt vmcnt(0)");      // tail: drain remaining
    }
    __builtin_amdgcn_sched_barrier(0);
    __builtin_amdgcn_s_barrier();              // every wave's tile t+1 landed
    cur ^= 1;
  }

  #pragma unroll
  for (int m = 0; m < 4; m++){
    int gr0 = m0 + wr * 64 + m * 16 + rq * 4;
    #pragma unroll
    for (int n = 0; n < 4; n++){
      int gc = n0 + wc * 64 + n * 16 + cl;
      #pragma unroll
      for (int rr = 0; rr < 4; rr++){
        if (OUT_BF16) ((u16*)Cout)[(size_t)(gr0 + rr) * N + gc] = f2bf(acc[m][n][rr]);
        else          ((float*)Cout)[(size_t)(gr0 + rr) * N + gc] = acc[m][n][rr];
      }
    }
  }
}

// ---------------- flash attention v4: paired q-tiles, QBLK=64, 2 blocks/CU ----------
// grid (bh=32 fast, pair p=0..15), 256 thr = 4 waves x 16 q-rows.
// Block: q-tile (31-p) [32-p tiles] then q-tile p [p+1 tiles] = exactly 33 iters.
// 512 blocks = exactly 2/CU -> barrier/drain of one block hides under the other's
// compute (m114 overlap). K dbuf + V = 48KB (96KB/CU); P overlays consumed K.
// Lean softmax: exp2 domain, ones-MFMA row-sum, defer-max gate. Direct write.

#define STAGE_K(jj, bsel) do {                                                            \
  _Pragma("unroll")                                                                       \
  for (int i_ = 0; i_ < 4; i_++){                                                         \
    int fb_ = (i_ * 4 + wv) * 64;                                                         \
    int p_  = (fb_ + lane) * 16;                                                          \
    int r_ = p_ >> 8; int cb_ = (p_ & 255) ^ ((r_ & 7) << 4);                             \
    gl_lds16(qkv + (size_t)(b * LL + (jj) * 64 + r_) * QKVN + HIDD + h * HDD + (cb_ >> 1),\
             &Kb[bsel][fb_ * 8]);                                                         \
  }                                                                                       \
} while(0)

#define STAGE_V(jj) do {                                                                  \
  _Pragma("unroll")                                                                       \
  for (int i_ = 0; i_ < 4; i_++){                                                         \
    int fb_ = (i_ * 4 + wv) * 64;                                                         \
    int p_  = (fb_ + lane) * 16;                                                          \
    int r_ = p_ >> 7; int cb_ = (p_ & 127) ^ ((r_ & 7) << 4);                             \
    gl_lds16(vt + (size_t)(bh * HDD + r_) * LL + (jj) * 64 + (cb_ >> 1), &Vs[fb_ * 8]);   \
  }                                                                                       \
} while(0)

__global__ __launch_bounds__(256, 2) void attn_k(
    const u16* __restrict__ qkv, const u16* __restrict__ vt,
    u16* __restrict__ aout)
{
  __shared__ __align__(16) u16 Kb[2][64 * 128];   // K tiles [64][128], 2x16KB
  __shared__ __align__(16) u16 Vs[128 * 64];      // V^T tile [128][64], 16KB
  const int tid = threadIdx.x, lane = tid & 63, wv = tid >> 6;
  const int bh = blockIdx.x;                      // fast dim -> XCD = bh % 8
  const int pr = blockIdx.y;                      // pair index 0..15
  const int b = bh >> 4, h = bh & 15;
  const int rq = lane >> 4, cl = lane & 15;

  bf16x8 ones;
  #pragma unroll
  for (int i = 0; i < 8; i++) ones[i] = (__bf16)1.0f;
  const f32x4 Z = {0.f, 0.f, 0.f, 0.f};

  int cur = 0;
  STAGE_K(0, 0);                                  // phase-A tile 0

  #pragma unroll
  for (int ph = 0; ph < 2; ph++){
    const int qt = ph ? pr : (31 - pr);           // 64-row q-tile index
    const int nj = qt + 1;

    // Q fragments for this q-tile: wave rows qt*64 + wv*16 + cl
    bf16x8 qf[4];
    {
      const u16* qb = qkv + (size_t)(b * LL + qt * 64 + wv * 16 + cl) * QKVN + h * HDD + rq * 8;
      #pragma unroll
      for (int ks = 0; ks < 4; ks++) qf[ks] = *(const bf16x8*)(qb + ks * 32);
    }

    f32x4 acco[8], accl;
    float mst[4];
    #pragma unroll
    for (int n = 0; n < 8; n++) acco[n] = Z;
    accl = Z;
    #pragma unroll
    for (int rr = 0; rr < 4; rr++) mst[rr] = -INFINITY;

    if (ph == 0) __syncthreads();                 // initial K landed

    for (int j = 0; j < nj; j++){
      // prefetch next K tile (crosses the phase boundary into phase B's j=0)
      if (j + 1 < nj)      STAGE_K(j + 1, cur ^ 1);
      else if (ph == 0)    STAGE_K(0,     cur ^ 1);
      STAGE_V(j);

      // S = Q K^T (16 q-rows x 64 kv per wave)
      f32x4 sv[4];
      {
        const char* KsC = (const char*)&Kb[cur][0];
        #pragma unroll
        for (int ct = 0; ct < 4; ct++) sv[ct] = Z;
        #pragma unroll
        for (int ks = 0; ks < 4; ks++){
          const int kb = ks * 64 + rq * 16;
          #pragma unroll
          for (int ct = 0; ct < 4; ct++){
            int r = ct * 16 + cl;
            bf16x8 bfr = *(const bf16x8*)(KsC + r * 256 + (kb ^ ((r & 7) << 4)));
            sv[ct] = __builtin_amdgcn_mfma_f32_16x16x32_bf16(qf[ks], bfr, sv[ct], 0, 0, 0);
          }
        }
      }

      __syncthreads();   // QK reads of Kb[cur] done; V (and next K) landed

      {
        char* pbase = (char*)&Kb[cur][0] + wv * 2048;   // P overlays consumed K
        const bool msk = (j == qt);                     // diagonal tile only

        float p4[4][4], lmx[4];
        #pragma unroll
        for (int rr = 0; rr < 4; rr++) lmx[rr] = -1e30f;
        const int qg = qt * 64 + wv * 16 + rq * 4;
        #pragma unroll
        for (int ct = 0; ct < 4; ct++){
          int col = j * 64 + ct * 16 + cl;
          #pragma unroll
          for (int rr = 0; rr < 4; rr++){
            float v = sv[ct][rr];                 // already log2-domain
            if (msk && col > qg + rr) v = -1e30f;
            p4[ct][rr] = v;
            lmx[rr] = fmaxf(lmx[rr], v);
          }
        }
        // defer-max gate
        float need = -1e30f;
        #pragma unroll
        for (int rr = 0; rr < 4; rr++) need = fmaxf(need, lmx[rr] - mst[rr]);
        if (__any(need > THR2)){
          float mx[4];
          #pragma unroll
          for (int rr = 0; rr < 4; rr++) mx[rr] = lmx[rr];
          #pragma unroll
          for (int off = 1; off < 16; off <<= 1)
            #pragma unroll
            for (int rr = 0; rr < 4; rr++)
              mx[rr] = fmaxf(mx[rr], __shfl_xor(mx[rr], off, 64));
          #pragma unroll
          for (int rr = 0; rr < 4; rr++){
            float mn  = fmaxf(mst[rr], mx[rr]);
            float fsc = exp2_fast(mst[rr] - mn);
            mst[rr] = mn;
            accl[rr] *= fsc;
            #pragma unroll
            for (int n = 0; n < 8; n++) acco[n][rr] *= fsc;
          }
        }
        #pragma unroll
        for (int ct = 0; ct < 4; ct++)
          #pragma unroll
          for (int rr = 0; rr < 4; rr++){
            float e = exp2_fast(p4[ct][rr] - mst[rr]);
            int wr = rq * 4 + rr;
            *(u16*)(pbase + wr * 128 + (((ct * 16 + cl) * 2) ^ ((wr & 7) << 4))) = f2bf(e);
          }

        // O += P V ; l += P 1
        const char* VsC = (const char*)Vs;
        #pragma unroll
        for (int ks = 0; ks < 2; ks++){
          const int kvb = ks * 64 + rq * 16;
          bf16x8 pa = *(const bf16x8*)(pbase + cl * 128 + (kvb ^ ((cl & 7) << 4)));
          accl = __builtin_amdgcn_mfma_f32_16x16x32_bf16(pa, ones, accl, 0, 0, 0);
          #pragma unroll
          for (int n = 0; n < 8; n++){
            int r = n * 16 + cl;
            bf16x8 bfr = *(const bf16x8*)(VsC + r * 128 + (kvb ^ ((r & 7) << 4)));
            acco[n] = __builtin_amdgcn_mfma_f32_16x16x32_bf16(pa, bfr, acco[n], 0, 0, 0);
          }
        }
      }

      __syncthreads();   // Vs + P reads done before next iter's staging
      cur ^= 1;
    }

    // direct write-out
    #pragma unroll
    for (int rr = 0; rr < 4; rr++){
      float inv = 1.0f / accl[rr];
      size_t grow = (size_t)(b * LL + qt * 64 + wv * 16 + rq * 4 + rr);
      #pragma unroll
      for (int n = 0; n < 8; n++)
        aout[grow * HIDD + h * HDD + n * 16 + cl] = f2bf(acco[n][rr] * inv);
    }
  }
}

// ---------------- launcher ----------------

extern "C" void kernel_launch(void* const* d_in, const int* in_sizes, int n_in,
                              void* d_out, int out_size, void* d_ws, size_t ws_size,
                              hipStream_t stream)
{
  const float* x  = (const float*)d_in[0];
  // d_in[1] = mask (causal; applied analytically)
  const float* Wq = (const float*)d_in[2];
  const float* Wk = (const float*)d_in[3];
  const float* Wv = (const float*)d_in[4];
  const float* Wo = (const float*)d_in[5];
  float* out = (float*)d_out;

  if (ws_size < 134217728ull) return;  // need 128 MB of scratch

  char* ws = (char*)d_ws;
  u16* xb   = (u16*)(ws);                  // 4096x2048 bf16  (16 MB)
  u16* Wt   = (u16*)(ws + 16777216ull);    // 6144x2048 bf16  (24 MB) = [Wq|Wk|Wv]^T
  u16* Wot  = (u16*)(ws + 41943040ull);    // 2048x2048 bf16  ( 8 MB)
  u16* qkv  = (u16*)(ws + 50331648ull);    // 4096x6144 bf16  (48 MB)
  u16* vt   = (u16*)(ws + 100663296ull);   // 32x128x2048 bf16(16 MB)
  u16* aout = (u16*)(ws + 117440512ull);   // 4096x2048 bf16  (16 MB)

  cvt_f32_bf16_k<<<2097152 / 256, 256, 0, stream>>>(x, xb, 2097152);
  transpose_cvt4_k<<<dim3(32, 32, 4), 256, 0, stream>>>(Wq, Wk, Wv, Wo, Wt, Wot);

  gemm_bt_k<1><<<dim3(6144 / 128, 4096 / 128), 256, 0, stream>>>(xb, Wt, qkv, 4096, 6144, 2048);
  rope_k<<<4194304 / 256, 256, 0, stream>>>(qkv);
  build_vt_k<<<dim3(4, 64, 32), dim3(32, 8), 0, stream>>>(qkv, vt);

  attn_k<<<dim3(32, 16), 256, 0, stream>>>(qkv, vt, aout);

  gemm_bt2_k<0><<<dim3(2048 / 256, 4096 / 128), 512, 0, stream>>>(aout, Wot, out, 4096, 2048, 2048);
}

// Round 13
// 265.013 us; speedup vs baseline: 1.1656x; 1.0147x over previous
//
#include <hip/hip_runtime.h>
#include <math.h>

#define BB   2
#define LL   2048
#define HIDD 2048
#define NHH  16
#define HDD  128
#define QKVN 6144   // 3*HIDD
#define THR2 11.5416f  // defer-max threshold, log2 domain (= 8 nats)

typedef unsigned short u16;
typedef float  f32x4 __attribute__((ext_vector_type(4)));
typedef __bf16 bf16x8 __attribute__((ext_vector_type(8)));

static __device__ __forceinline__ float exp2_fast(float x){
  return __builtin_amdgcn_exp2f(x);    // v_exp_f32 (native 2^x)
}
static __device__ __forceinline__ u16 f2bf(float x){
  unsigned u = __float_as_uint(x);
  return (u16)((u + 0x7fffu + ((u >> 16) & 1u)) >> 16);
}
static __device__ __forceinline__ float bf2f(u16 b){
  return __uint_as_float(((unsigned)b) << 16);
}
static __device__ __forceinline__ void gl_lds16(const void* g, void* l){
  __builtin_amdgcn_global_load_lds(
      (__attribute__((address_space(1))) void*)(void*)g,
      (__attribute__((address_space(3))) void*)l,
      16, 0, 0);
}

// ---------------- prep kernels ----------------

__global__ void cvt_f32_bf16_k(const float* __restrict__ src, u16* __restrict__ dst, int n4){
  int i = blockIdx.x * blockDim.x + threadIdx.x;
  if (i >= n4) return;
  float4 v = ((const float4*)src)[i];
  ushort4 o;
  o.x = f2bf(v.x); o.y = f2bf(v.y); o.z = f2bf(v.z); o.w = f2bf(v.w);
  ((ushort4*)dst)[i] = o;
}

// fused 4x (2048^2 f32 -> transposed bf16). grid (32,32,4), 256 thr, 64x64 tiles.
__global__ __launch_bounds__(256) void transpose_cvt4_k(
    const float* __restrict__ Wq, const float* __restrict__ Wk,
    const float* __restrict__ Wv, const float* __restrict__ Wo,
    u16* __restrict__ Wt, u16* __restrict__ Wot)
{
  __shared__ u16 t[64][66];
  const int z = blockIdx.z;
  const float* src = (z == 0) ? Wq : (z == 1) ? Wk : (z == 2) ? Wv : Wo;
  u16* dst = (z == 3) ? Wot : (Wt + (size_t)z * 2048 * 2048);
  const int c0 = blockIdx.x * 64, r0 = blockIdx.y * 64;
  const int tid = threadIdx.x;

  #pragma unroll
  for (int i = 0; i < 4; i++){
    int r  = i * 16 + (tid >> 4);
    int c4 = (tid & 15) * 4;
    float4 v = *(const float4*)&src[(size_t)(r0 + r) * 2048 + c0 + c4];
    t[c4 + 0][r] = f2bf(v.x);
    t[c4 + 1][r] = f2bf(v.y);
    t[c4 + 2][r] = f2bf(v.z);
    t[c4 + 3][r] = f2bf(v.w);
  }
  __syncthreads();
  #pragma unroll
  for (int i = 0; i < 2; i++){
    int c  = i * 32 + (tid >> 3);
    int rs = (tid & 7) * 8;
    const unsigned* p = (const unsigned*)&t[c][rs];   // 4B-aligned
    unsigned w0 = p[0], w1 = p[1], w2 = p[2], w3 = p[3];
    u16* d = &dst[(size_t)(c0 + c) * 2048 + r0 + rs];
    ((unsigned*)d)[0] = w0; ((unsigned*)d)[1] = w1;
    ((unsigned*)d)[2] = w2; ((unsigned*)d)[3] = w3;
  }
}

// in-place RoPE on q,k sections of qkv (bf16). idx over B*L*NH*64
// Q additionally pre-scaled by 1/sqrt(128)*log2(e) -> scores in exp2 domain.
__global__ void rope_k(u16* __restrict__ qkv){
  int idx = blockIdx.x * blockDim.x + threadIdx.x;
  int d   = idx & 63;
  int h   = (idx >> 6) & 15;
  int row = idx >> 10;           // b*L + l
  int l   = row & (LL - 1);
  float fr = __expf(-(float)d * 0.17988946f);   // ln(1e5)/64
  float th = (float)l * 0.25f * fr;             // pos/ROPE_SCALE * freq
  float s, c;
  sincosf(th, &s, &c);
  size_t base = (size_t)row * QKVN + h * HDD + d;
  #pragma unroll
  for (int part = 0; part < 2; part++){         // q then k
    float f = (part == 0) ? 0.12753375f : 1.0f; // scale*log2e folded into Q
    float x1 = bf2f(qkv[base]), x2 = bf2f(qkv[base + 64]);
    qkv[base]      = f2bf((x1 * c - x2 * s) * f);
    qkv[base + 64] = f2bf((x1 * s + x2 * c) * f);
    base += HIDD;
  }
}

// v section of qkv -> vt[(b,h), d, l]
__global__ void build_vt_k(const u16* __restrict__ qkv, u16* __restrict__ vt){
  __shared__ u16 t[32][33];
  int bh = blockIdx.z;
  int b = bh >> 4, h = bh & 15;
  const u16* src = qkv + (size_t)b * LL * QKVN + 2 * HIDD + h * HDD; // [l][d] stride QKVN
  u16* dst = vt + (size_t)bh * HDD * LL;                              // [d][l] stride LL
  int d0 = blockIdx.x * 32, l0 = blockIdx.y * 32;
  int tx = threadIdx.x, ty = threadIdx.y;
  #pragma unroll
  for (int i = 0; i < 32; i += 8) t[ty + i][tx] = src[(size_t)(l0 + ty + i) * QKVN + d0 + tx];
  __syncthreads();
  #pragma unroll
  for (int i = 0; i < 32; i += 8) dst[(size_t)(d0 + ty + i) * LL + l0 + tx] = t[tx][ty + i];
}

// ---------------- GEMM 128x128 (proven for gemm1): C = A * Bt^T ----------------

template<int OUT_BF16>
__global__ __launch_bounds__(256) void gemm_bt_k(
    const u16* __restrict__ A, const u16* __restrict__ Bt,
    void* __restrict__ Cout, int M, int N, int K)
{
  __shared__ __align__(16) u16 As[128 * 64];
  __shared__ __align__(16) u16 Bs[128 * 64];
  const int tid = threadIdx.x, lane = tid & 63, wv = tid >> 6;
  const int wr = wv >> 1, wc = wv & 1;
  const int m0 = blockIdx.y * 128, n0 = blockIdx.x * 128;
  const int rq = lane >> 4, cl = lane & 15;

  const f32x4 Z = {0.f, 0.f, 0.f, 0.f};
  f32x4 acc[4][4];
  #pragma unroll
  for (int m = 0; m < 4; m++)
    #pragma unroll
    for (int n = 0; n < 4; n++) acc[m][n] = Z;

  for (int kt = 0; kt < K; kt += 64){
    #pragma unroll
    for (int i = 0; i < 4; i++){
      int fb = (i * 4 + wv) * 64;          // wave-uniform 16B-chunk base
      int p  = (fb + lane) * 16;           // this lane's physical LDS byte
      int r  = p >> 7;                     // tile row (128B rows)
      int cbs = (p & 127) ^ ((r & 7) << 4);
      gl_lds16(A  + (size_t)(m0 + r) * K + kt + (cbs >> 1), &As[fb * 8]);
      gl_lds16(Bt + (size_t)(n0 + r) * K + kt + (cbs >> 1), &Bs[fb * 8]);
    }
    __syncthreads();
    #pragma unroll
    for (int ks = 0; ks < 2; ks++){
      const int kb = ks * 64 + rq * 16;    // k byte offset in row
      bf16x8 a[4], b[4];
      #pragma unroll
      for (int m = 0; m < 4; m++){
        int r = wr * 64 + m * 16 + cl;
        a[m] = *(const bf16x8*)((const char*)As + r * 128 + (kb ^ ((r & 7) << 4)));
      }
      #pragma unroll
      for (int n = 0; n < 4; n++){
        int r = wc * 64 + n * 16 + cl;
        b[n] = *(const bf16x8*)((const char*)Bs + r * 128 + (kb ^ ((r & 7) << 4)));
      }
      #pragma unroll
      for (int m = 0; m < 4; m++)
        #pragma unroll
        for (int n = 0; n < 4; n++)
          acc[m][n] = __builtin_amdgcn_mfma_f32_16x16x32_bf16(a[m], b[n], acc[m][n], 0, 0, 0);
    }
    __syncthreads();
  }

  #pragma unroll
  for (int m = 0; m < 4; m++){
    int gr0 = m0 + wr * 64 + m * 16 + rq * 4;
    #pragma unroll
    for (int n = 0; n < 4; n++){
      int gc = n0 + wc * 64 + n * 16 + cl;
      #pragma unroll
      for (int rr = 0; rr < 4; rr++){
        if (OUT_BF16) ((u16*)Cout)[(size_t)(gr0 + rr) * N + gc] = f2bf(acc[m][n][rr]);
        else          ((float*)Cout)[(size_t)(gr0 + rr) * N + gc] = acc[m][n][rr];
      }
    }
  }
}

// ---------------- GEMM 128x256 counted-vmcnt (proven for gemm2) ----------------

#define G2_STAGE(kt, bsel) do {                                                           \
  _Pragma("unroll")                                                                       \
  for (int i_ = 0; i_ < 2; i_++){     /* A: 128x64 = 1024 chunks */                       \
    int c_ = ((i_ * 8 + wv) * 64) + lane;                                                 \
    int p_ = c_ * 16;                                                                     \
    int r_ = p_ >> 7; int cb_ = (p_ & 127) ^ ((r_ & 7) << 4);                             \
    gl_lds16(A + (size_t)(m0 + r_) * K + (kt) + (cb_ >> 1),                               \
             &AB[bsel][((i_ * 8 + wv) * 64) * 8]);                                        \
  }                                                                                       \
  _Pragma("unroll")                                                                       \
  for (int i_ = 0; i_ < 4; i_++){     /* B: 256x64 = 2048 chunks */                       \
    int c_ = ((i_ * 8 + wv) * 64) + lane;                                                 \
    int p_ = c_ * 16;                                                                     \
    int r_ = p_ >> 7; int cb_ = (p_ & 127) ^ ((r_ & 7) << 4);                             \
    gl_lds16(Bt + (size_t)(n0 + r_) * K + (kt) + (cb_ >> 1),                              \
             &AB[bsel][8192 + ((i_ * 8 + wv) * 64) * 8]);                                 \
  }                                                                                       \
} while(0)

template<int OUT_BF16>
__global__ __launch_bounds__(512, 1) void gemm_bt2_k(
    const u16* __restrict__ A, const u16* __restrict__ Bt,
    void* __restrict__ Cout, int M, int N, int K)
{
  __shared__ __align__(16) u16 AB[2][24576];   // per buf: A[128][64] @0, B[256][64] @8192
  const int tid = threadIdx.x, lane = tid & 63, wv = tid >> 6;
  const int wr = wv >> 2, wc = wv & 3;          // 2 (M) x 4 (N) waves
  const int m0 = blockIdx.y * 128, n0 = blockIdx.x * 256;
  const int rq = lane >> 4, cl = lane & 15;
  const int NT = K >> 6;                        // 64-wide K tiles

  const f32x4 Z = {0.f, 0.f, 0.f, 0.f};
  f32x4 acc[4][4];
  #pragma unroll
  for (int m = 0; m < 4; m++)
    #pragma unroll
    for (int n = 0; n < 4; n++) acc[m][n] = Z;

  G2_STAGE(0, 0);
  G2_STAGE(64, 1);
  asm volatile("s_waitcnt vmcnt(6)");
  __builtin_amdgcn_sched_barrier(0);
  __builtin_amdgcn_s_barrier();

  int cur = 0;
  for (int t = 0; t < NT; t++){
    const char* As_ = (const char*)&AB[cur][0];
    const char* Bs_ = (const char*)&AB[cur][8192];

    #pragma unroll
    for (int ks = 0; ks < 2; ks++){
      const int kb = ks * 64 + rq * 16;
      bf16x8 a[4], b[4];
      #pragma unroll
      for (int m = 0; m < 4; m++){
        int r = wr * 64 + m * 16 + cl;
        a[m] = *(const bf16x8*)(As_ + r * 128 + (kb ^ ((r & 7) << 4)));
      }
      #pragma unroll
      for (int n = 0; n < 4; n++){
        int r = wc * 64 + n * 16 + cl;
        b[n] = *(const bf16x8*)(Bs_ + r * 128 + (kb ^ ((r & 7) << 4)));
      }
      __builtin_amdgcn_s_setprio(1);
      #pragma unroll
      for (int m = 0; m < 4; m++)
        #pragma unroll
        for (int n = 0; n < 4; n++)
          acc[m][n] = __builtin_amdgcn_mfma_f32_16x16x32_bf16(a[m], b[n], acc[m][n], 0, 0, 0);
      __builtin_amdgcn_s_setprio(0);
    }

    __builtin_amdgcn_sched_barrier(0);
    __builtin_amdgcn_s_barrier();              // every wave done READING buf[cur]

    if (t + 2 < NT){
      G2_STAGE((t + 2) * 64, cur);             // overwrite freed buffer
      asm volatile("s_waitcnt vmcnt(6)");      // tile t+1 landed; t+2 stays in flight
    } else {
      asm volatile("s_waitcnt vmcnt(0)");      // tail: drain remaining
    }
    __builtin_amdgcn_sched_barrier(0);
    __builtin_amdgcn_s_barrier();              // every wave's tile t+1 landed
    cur ^= 1;
  }

  #pragma unroll
  for (int m = 0; m < 4; m++){
    int gr0 = m0 + wr * 64 + m * 16 + rq * 4;
    #pragma unroll
    for (int n = 0; n < 4; n++){
      int gc = n0 + wc * 64 + n * 16 + cl;
      #pragma unroll
      for (int rr = 0; rr < 4; rr++){
        if (OUT_BF16) ((u16*)Cout)[(size_t)(gr0 + rr) * N + gc] = f2bf(acc[m][n][rr]);
        else          ((float*)Cout)[(size_t)(gr0 + rr) * N + gc] = acc[m][n][rr];
      }
    }
  }
}

// ---------------- flash attention v5: counted-vmcnt pipeline (T4 for attn) ----------
// grid (bh=32 fast, pair p=0..15), 256 thr = 4 waves x 16 q-rows, 2 blocks/CU.
// Block: q-tile (31-p) then q-tile p = exactly 33 iters. LDS: K dbuf 32KB + V 16KB
// + P 8KB = 56KB. Per iter: issue V(j) then K(j+1) -> vmcnt(8)+bar (K(j) landed,
// V+Knext in flight) -> QK -> softmax/P -> vmcnt(4)+bar (V landed, Knext flying)
// -> PV -> bar. vmcnt never drains to 0 mid-loop.

#define STAGE_K(jj, bsel) do {                                                            \
  _Pragma("unroll")                                                                       \
  for (int i_ = 0; i_ < 4; i_++){                                                         \
    int fb_ = (i_ * 4 + wv) * 64;                                                         \
    int p_  = (fb_ + lane) * 16;                                                          \
    int r_ = p_ >> 8; int cb_ = (p_ & 255) ^ ((r_ & 7) << 4);                             \
    gl_lds16(qkv + (size_t)(b * LL + (jj) * 64 + r_) * QKVN + HIDD + h * HDD + (cb_ >> 1),\
             &Kb[bsel][fb_ * 8]);                                                         \
  }                                                                                       \
} while(0)

#define STAGE_V(jj) do {                                                                  \
  _Pragma("unroll")                                                                       \
  for (int i_ = 0; i_ < 4; i_++){                                                         \
    int fb_ = (i_ * 4 + wv) * 64;                                                         \
    int p_  = (fb_ + lane) * 16;                                                          \
    int r_ = p_ >> 7; int cb_ = (p_ & 127) ^ ((r_ & 7) << 4);                             \
    gl_lds16(vt + (size_t)(bh * HDD + r_) * LL + (jj) * 64 + (cb_ >> 1), &Vs[fb_ * 8]);   \
  }                                                                                       \
} while(0)

__global__ __launch_bounds__(256, 2) void attn_k(
    const u16* __restrict__ qkv, const u16* __restrict__ vt,
    u16* __restrict__ aout)
{
  __shared__ __align__(16) u16 Kb[2][64 * 128];   // K tiles [64][128], 2x16KB
  __shared__ __align__(16) u16 Vs[128 * 64];      // V^T tile [128][64], 16KB
  __shared__ __align__(16) u16 Ps[4][1024];       // per-wave P tile 16x64, 8KB
  const int tid = threadIdx.x, lane = tid & 63, wv = tid >> 6;
  const int bh = blockIdx.x;                      // fast dim -> XCD = bh % 8
  const int pr = blockIdx.y;                      // pair index 0..15
  const int b = bh >> 4, h = bh & 15;
  const int rq = lane >> 4, cl = lane & 15;

  bf16x8 ones;
  #pragma unroll
  for (int i = 0; i < 8; i++) ones[i] = (__bf16)1.0f;
  const f32x4 Z = {0.f, 0.f, 0.f, 0.f};

  int cur = 0;
  STAGE_K(0, 0);                                  // phase-A tile 0
  asm volatile("s_waitcnt vmcnt(0)" ::: "memory");
  __builtin_amdgcn_sched_barrier(0);
  __builtin_amdgcn_s_barrier();

  #pragma unroll
  for (int ph = 0; ph < 2; ph++){
    const int qt = ph ? pr : (31 - pr);           // 64-row q-tile index
    const int nj = qt + 1;

    // Q fragments for this q-tile: wave rows qt*64 + wv*16 + cl
    bf16x8 qf[4];
    {
      const u16* qb = qkv + (size_t)(b * LL + qt * 64 + wv * 16 + cl) * QKVN + h * HDD + rq * 8;
      #pragma unroll
      for (int ks = 0; ks < 4; ks++) qf[ks] = *(const bf16x8*)(qb + ks * 32);
    }

    f32x4 acco[8], accl;
    float mst[4];
    #pragma unroll
    for (int n = 0; n < 8; n++) acco[n] = Z;
    accl = Z;
    #pragma unroll
    for (int rr = 0; rr < 4; rr++) mst[rr] = -INFINITY;

    for (int j = 0; j < nj; j++){
      const bool sn = (j + 1 < nj) || (ph == 0);  // will stage a next-K this iter
      STAGE_V(j);                                  // older in vm queue
      if (j + 1 < nj)      STAGE_K(j + 1, cur ^ 1);
      else if (ph == 0)    STAGE_K(0,     cur ^ 1);  // cross into phase B
      __builtin_amdgcn_sched_barrier(0);
      if (sn) asm volatile("s_waitcnt vmcnt(8)" ::: "memory");  // K(j) landed
      else    asm volatile("s_waitcnt vmcnt(4)" ::: "memory");
      __builtin_amdgcn_sched_barrier(0);
      __builtin_amdgcn_s_barrier();               // all waves' K(j) landed
      __builtin_amdgcn_sched_barrier(0);

      // S = Q K^T (16 q-rows x 64 kv per wave)
      f32x4 sv[4];
      {
        const char* KsC = (const char*)&Kb[cur][0];
        #pragma unroll
        for (int ct = 0; ct < 4; ct++) sv[ct] = Z;
        #pragma unroll
        for (int ks = 0; ks < 4; ks++){
          const int kb = ks * 64 + rq * 16;
          #pragma unroll
          for (int ct = 0; ct < 4; ct++){
            int r = ct * 16 + cl;
            bf16x8 bfr = *(const bf16x8*)(KsC + r * 256 + (kb ^ ((r & 7) << 4)));
            sv[ct] = __builtin_amdgcn_mfma_f32_16x16x32_bf16(qf[ks], bfr, sv[ct], 0, 0, 0);
          }
        }
      }

      // softmax (exp2 domain) + P write into own Ps slot (no barrier needed)
      {
        char* pbase = (char*)&Ps[wv][0];
        const bool msk = (j == qt);                 // diagonal tile only

        float p4[4][4], lmx[4];
        #pragma unroll
        for (int rr = 0; rr < 4; rr++) lmx[rr] = -1e30f;
        const int qg = qt * 64 + wv * 16 + rq * 4;
        #pragma unroll
        for (int ct = 0; ct < 4; ct++){
          int col = j * 64 + ct * 16 + cl;
          #pragma unroll
          for (int rr = 0; rr < 4; rr++){
            float v = sv[ct][rr];                   // already log2-domain
            if (msk && col > qg + rr) v = -1e30f;
            p4[ct][rr] = v;
            lmx[rr] = fmaxf(lmx[rr], v);
          }
        }
        // defer-max gate
        float need = -1e30f;
        #pragma unroll
        for (int rr = 0; rr < 4; rr++) need = fmaxf(need, lmx[rr] - mst[rr]);
        if (__any(need > THR2)){
          float mx[4];
          #pragma unroll
          for (int rr = 0; rr < 4; rr++) mx[rr] = lmx[rr];
          #pragma unroll
          for (int off = 1; off < 16; off <<= 1)
            #pragma unroll
            for (int rr = 0; rr < 4; rr++)
              mx[rr] = fmaxf(mx[rr], __shfl_xor(mx[rr], off, 64));
          #pragma unroll
          for (int rr = 0; rr < 4; rr++){
            float mn  = fmaxf(mst[rr], mx[rr]);
            float fsc = exp2_fast(mst[rr] - mn);
            mst[rr] = mn;
            accl[rr] *= fsc;
            #pragma unroll
            for (int n = 0; n < 8; n++) acco[n][rr] *= fsc;
          }
        }
        #pragma unroll
        for (int ct = 0; ct < 4; ct++)
          #pragma unroll
          for (int rr = 0; rr < 4; rr++){
            float e = exp2_fast(p4[ct][rr] - mst[rr]);
            int wr = rq * 4 + rr;
            *(u16*)(pbase + wr * 128 + (((ct * 16 + cl) * 2) ^ ((wr & 7) << 4))) = f2bf(e);
          }
      }

      __builtin_amdgcn_sched_barrier(0);
      if (sn) asm volatile("s_waitcnt vmcnt(4)" ::: "memory");  // V(j) landed
      else    asm volatile("s_waitcnt vmcnt(0)" ::: "memory");
      __builtin_amdgcn_sched_barrier(0);
      __builtin_amdgcn_s_barrier();               // all waves' V(j) landed
      __builtin_amdgcn_sched_barrier(0);

      // O += P V ; l += P 1
      {
        const char* VsC = (const char*)Vs;
        char* pbase = (char*)&Ps[wv][0];
        #pragma unroll
        for (int ks = 0; ks < 2; ks++){
          const int kvb = ks * 64 + rq * 16;
          bf16x8 pa = *(const bf16x8*)(pbase + cl * 128 + (kvb ^ ((cl & 7) << 4)));
          accl = __builtin_amdgcn_mfma_f32_16x16x32_bf16(pa, ones, accl, 0, 0, 0);
          #pragma unroll
          for (int n = 0; n < 8; n++){
            int r = n * 16 + cl;
            bf16x8 bfr = *(const bf16x8*)(VsC + r * 128 + (kvb ^ ((r & 7) << 4)));
            acco[n] = __builtin_amdgcn_mfma_f32_16x16x32_bf16(pa, bfr, acco[n], 0, 0, 0);
          }
        }
      }

      __builtin_amdgcn_sched_barrier(0);
      __builtin_amdgcn_s_barrier();               // all done reading Vs before next STAGE_V
      __builtin_amdgcn_sched_barrier(0);
      cur ^= 1;
    }

    // direct write-out
    #pragma unroll
    for (int rr = 0; rr < 4; rr++){
      float inv = 1.0f / accl[rr];
      size_t grow = (size_t)(b * LL + qt * 64 + wv * 16 + rq * 4 + rr);
      #pragma unroll
      for (int n = 0; n < 8; n++)
        aout[grow * HIDD + h * HDD + n * 16 + cl] = f2bf(acco[n][rr] * inv);
    }
  }
}

// ---------------- launcher ----------------

extern "C" void kernel_launch(void* const* d_in, const int* in_sizes, int n_in,
                              void* d_out, int out_size, void* d_ws, size_t ws_size,
                              hipStream_t stream)
{
  const float* x  = (const float*)d_in[0];
  // d_in[1] = mask (causal; applied analytically)
  const float* Wq = (const float*)d_in[2];
  const float* Wk = (const float*)d_in[3];
  const float* Wv = (const float*)d_in[4];
  const float* Wo = (const float*)d_in[5];
  float* out = (float*)d_out;

  if (ws_size < 134217728ull) return;  // need 128 MB of scratch

  char* ws = (char*)d_ws;
  u16* xb   = (u16*)(ws);                  // 4096x2048 bf16  (16 MB)
  u16* Wt   = (u16*)(ws + 16777216ull);    // 6144x2048 bf16  (24 MB) = [Wq|Wk|Wv]^T
  u16* Wot  = (u16*)(ws + 41943040ull);    // 2048x2048 bf16  ( 8 MB)
  u16* qkv  = (u16*)(ws + 50331648ull);    // 4096x6144 bf16  (48 MB)
  u16* vt   = (u16*)(ws + 100663296ull);   // 32x128x2048 bf16(16 MB)
  u16* aout = (u16*)(ws + 117440512ull);   // 4096x2048 bf16  (16 MB)

  cvt_f32_bf16_k<<<2097152 / 256, 256, 0, stream>>>(x, xb, 2097152);
  transpose_cvt4_k<<<dim3(32, 32, 4), 256, 0, stream>>>(Wq, Wk, Wv, Wo, Wt, Wot);

  gemm_bt_k<1><<<dim3(6144 / 128, 4096 / 128), 256, 0, stream>>>(xb, Wt, qkv, 4096, 6144, 2048);
  rope_k<<<4194304 / 256, 256, 0, stream>>>(qkv);
  build_vt_k<<<dim3(4, 64, 32), dim3(32, 8), 0, stream>>>(qkv, vt);

  attn_k<<<dim3(32, 16), 256, 0, stream>>>(qkv, vt, aout);

  gemm_bt2_k<0><<<dim3(2048 / 256, 4096 / 128), 512, 0, stream>>>(aout, Wot, out, 4096, 2048, 2048);
}

// Round 14
// 261.319 us; speedup vs baseline: 1.1820x; 1.0141x over previous
//
#include <hip/hip_runtime.h>
#include <math.h>

#define BB   2
#define LL   2048
#define HIDD 2048
#define NHH  16
#define HDD  128
#define QKN  4096   // q|k buffer row stride (v goes straight to vt)
#define THR2 11.5416f  // defer-max threshold, log2 domain (= 8 nats)

typedef unsigned short u16;
typedef float  f32x4 __attribute__((ext_vector_type(4)));
typedef __bf16 bf16x8 __attribute__((ext_vector_type(8)));

static __device__ __forceinline__ float exp2_fast(float x){
  return __builtin_amdgcn_exp2f(x);    // v_exp_f32 (native 2^x)
}
static __device__ __forceinline__ u16 f2bf(float x){
  unsigned u = __float_as_uint(x);
  return (u16)((u + 0x7fffu + ((u >> 16) & 1u)) >> 16);
}
static __device__ __forceinline__ float bf2f(u16 b){
  return __uint_as_float(((unsigned)b) << 16);
}
static __device__ __forceinline__ void gl_lds16(const void* g, void* l){
  __builtin_amdgcn_global_load_lds(
      (__attribute__((address_space(1))) void*)(void*)g,
      (__attribute__((address_space(3))) void*)l,
      16, 0, 0);
}

// ---------------- prep kernels ----------------

__global__ void cvt_f32_bf16_k(const float* __restrict__ src, u16* __restrict__ dst, int n4){
  int i = blockIdx.x * blockDim.x + threadIdx.x;
  if (i >= n4) return;
  float4 v = ((const float4*)src)[i];
  ushort4 o;
  o.x = f2bf(v.x); o.y = f2bf(v.y); o.z = f2bf(v.z); o.w = f2bf(v.w);
  ((ushort4*)dst)[i] = o;
}

// cos/sin table: tab[l*64+d] = (cos(th), sin(th)), th = (l/4)*exp(-d*ln(1e5)/64)
__global__ void rope_table_k(float2* __restrict__ tab){
  int idx = blockIdx.x * blockDim.x + threadIdx.x;   // 2048*64
  int l = idx >> 6, d = idx & 63;
  float fr = __expf(-(float)d * 0.17988946f);
  float th = (float)l * 0.25f * fr;
  float s, c;
  sincosf(th, &s, &c);
  tab[idx] = make_float2(c, s);
}

// fused 4x (2048^2 f32 -> transposed bf16). grid (32,32,4), 256 thr, 64x64 tiles.
__global__ __launch_bounds__(256) void transpose_cvt4_k(
    const float* __restrict__ Wq, const float* __restrict__ Wk,
    const float* __restrict__ Wv, const float* __restrict__ Wo,
    u16* __restrict__ Wt, u16* __restrict__ Wot)
{
  __shared__ u16 t[64][66];
  const int z = blockIdx.z;
  const float* src = (z == 0) ? Wq : (z == 1) ? Wk : (z == 2) ? Wv : Wo;
  u16* dst = (z == 3) ? Wot : (Wt + (size_t)z * 2048 * 2048);
  const int c0 = blockIdx.x * 64, r0 = blockIdx.y * 64;
  const int tid = threadIdx.x;

  #pragma unroll
  for (int i = 0; i < 4; i++){
    int r  = i * 16 + (tid >> 4);
    int c4 = (tid & 15) * 4;
    float4 v = *(const float4*)&src[(size_t)(r0 + r) * 2048 + c0 + c4];
    t[c4 + 0][r] = f2bf(v.x);
    t[c4 + 1][r] = f2bf(v.y);
    t[c4 + 2][r] = f2bf(v.z);
    t[c4 + 3][r] = f2bf(v.w);
  }
  __syncthreads();
  #pragma unroll
  for (int i = 0; i < 2; i++){
    int c  = i * 32 + (tid >> 3);
    int rs = (tid & 7) * 8;
    const unsigned* p = (const unsigned*)&t[c][rs];   // 4B-aligned
    unsigned w0 = p[0], w1 = p[1], w2 = p[2], w3 = p[3];
    u16* d = &dst[(size_t)(c0 + c) * 2048 + r0 + rs];
    ((unsigned*)d)[0] = w0; ((unsigned*)d)[1] = w1;
    ((unsigned*)d)[2] = w2; ((unsigned*)d)[3] = w3;
  }
}

// ---------------- GEMM 128x128 with fused RoPE/V^T epilogue (gemm1) ----------------
// K-loop identical to the proven 119us kernel. Epilogue (per 128x128 tile = one
// head of one section): stage acc->LDS bf16 (stride 130, bank-spread), then
//  sec 0/1 (q/k): rope pairs (d, d+64) via table, q pre-scaled, write to qk.
//  sec 2   (v)  : write transposed into vt ([bh][d][l], 128B contiguous/thread).

__global__ __launch_bounds__(256) void gemm_qkv_k(
    const u16* __restrict__ A, const u16* __restrict__ Bt,
    u16* __restrict__ qk, u16* __restrict__ vt,
    const float2* __restrict__ rtab, int M, int N, int K)
{
  __shared__ __align__(16) u16 SH[16640];      // K-loop: As=SH[0..8191], Bs=SH[8192..16383]
  u16* As = SH;
  u16* Bs = SH + 8192;
  const int tid = threadIdx.x, lane = tid & 63, wv = tid >> 6;
  const int wr = wv >> 1, wc = wv & 1;
  const int m0 = blockIdx.y * 128, n0 = blockIdx.x * 128;
  const int rq = lane >> 4, cl = lane & 15;

  const f32x4 Z = {0.f, 0.f, 0.f, 0.f};
  f32x4 acc[4][4];
  #pragma unroll
  for (int m = 0; m < 4; m++)
    #pragma unroll
    for (int n = 0; n < 4; n++) acc[m][n] = Z;

  for (int kt = 0; kt < K; kt += 64){
    #pragma unroll
    for (int i = 0; i < 4; i++){
      int fb = (i * 4 + wv) * 64;          // wave-uniform 16B-chunk base
      int p  = (fb + lane) * 16;           // this lane's physical LDS byte
      int r  = p >> 7;                     // tile row (128B rows)
      int cbs = (p & 127) ^ ((r & 7) << 4);
      gl_lds16(A  + (size_t)(m0 + r) * K + kt + (cbs >> 1), &As[fb * 8]);
      gl_lds16(Bt + (size_t)(n0 + r) * K + kt + (cbs >> 1), &Bs[fb * 8]);
    }
    __syncthreads();
    #pragma unroll
    for (int ks = 0; ks < 2; ks++){
      const int kb = ks * 64 + rq * 16;    // k byte offset in row
      bf16x8 a[4], b[4];
      #pragma unroll
      for (int m = 0; m < 4; m++){
        int r = wr * 64 + m * 16 + cl;
        a[m] = *(const bf16x8*)((const char*)As + r * 128 + (kb ^ ((r & 7) << 4)));
      }
      #pragma unroll
      for (int n = 0; n < 4; n++){
        int r = wc * 64 + n * 16 + cl;
        b[n] = *(const bf16x8*)((const char*)Bs + r * 128 + (kb ^ ((r & 7) << 4)));
      }
      #pragma unroll
      for (int m = 0; m < 4; m++)
        #pragma unroll
        for (int n = 0; n < 4; n++)
          acc[m][n] = __builtin_amdgcn_mfma_f32_16x16x32_bf16(a[m], b[n], acc[m][n], 0, 0, 0);
    }
    __syncthreads();
  }

  // ---- fused epilogue ----
  const int hd  = n0 >> 7;       // head-column 0..47
  const int sec = hd >> 4;       // 0=q, 1=k, 2=v
  const int hh  = hd & 15;

  // stage acc -> LDS bf16, stride 130 (bank-spread for the re-read patterns)
  #pragma unroll
  for (int m = 0; m < 4; m++){
    int gr0 = wr * 64 + m * 16 + rq * 4;
    #pragma unroll
    for (int n = 0; n < 4; n++){
      int gc = wc * 64 + n * 16 + cl;
      #pragma unroll
      for (int rr = 0; rr < 4; rr++)
        SH[(gr0 + rr) * 130 + gc] = f2bf(acc[m][n][rr]);
    }
  }
  __syncthreads();

  if (sec < 2){
    // rope: thread t -> row r = t>>1, d in [dbase, dbase+32)
    const float fsc = (sec == 0) ? 0.12753375f : 1.0f;   // q: 1/sqrt(128)*log2e
    const int r = tid >> 1, dbase = (tid & 1) * 32;
    const int l = (m0 + r) & (LL - 1);
    const float2* tab = rtab + l * 64 + dbase;
    u16* orow = qk + (size_t)(m0 + r) * QKN + hd * 128;
    #pragma unroll
    for (int g = 0; g < 4; g++){
      bf16x8 o1, o2;
      #pragma unroll
      for (int i = 0; i < 8; i++){
        int d = g * 8 + i;
        float2 cs = tab[d];
        float x1 = bf2f(SH[r * 130 + dbase + d]);
        float x2 = bf2f(SH[r * 130 + dbase + d + 64]);
        o1[i] = (__bf16)((x1 * cs.x - x2 * cs.y) * fsc);
        o2[i] = (__bf16)((x1 * cs.y + x2 * cs.x) * fsc);
      }
      *(bf16x8*)(orow + dbase + g * 8)      = o1;
      *(bf16x8*)(orow + dbase + 64 + g * 8) = o2;
    }
  } else {
    // v: thread t -> d = t>>1, l-half l0 = (t&1)*64; write vt[bh][d][l] contiguous
    const int d = tid >> 1, l0 = (tid & 1) * 64;
    const int bh = ((m0 >> 11) << 4) + hh;
    u16* vrow = vt + ((size_t)bh * HDD + d) * LL + (m0 & (LL - 1)) + l0;
    #pragma unroll
    for (int g = 0; g < 8; g++){
      bf16x8 o;
      #pragma unroll
      for (int i = 0; i < 8; i++)
        o[i] = *(__bf16*)&SH[(l0 + g * 8 + i) * 130 + d];
      *(bf16x8*)(vrow + g * 8) = o;
    }
  }
}

// ---------------- GEMM 128x256 counted-vmcnt (proven for gemm2) ----------------

#define G2_STAGE(kt, bsel) do {                                                           \
  _Pragma("unroll")                                                                       \
  for (int i_ = 0; i_ < 2; i_++){     /* A: 128x64 = 1024 chunks */                       \
    int c_ = ((i_ * 8 + wv) * 64) + lane;                                                 \
    int p_ = c_ * 16;                                                                     \
    int r_ = p_ >> 7; int cb_ = (p_ & 127) ^ ((r_ & 7) << 4);                             \
    gl_lds16(A + (size_t)(m0 + r_) * K + (kt) + (cb_ >> 1),                               \
             &AB[bsel][((i_ * 8 + wv) * 64) * 8]);                                        \
  }                                                                                       \
  _Pragma("unroll")                                                                       \
  for (int i_ = 0; i_ < 4; i_++){     /* B: 256x64 = 2048 chunks */                       \
    int c_ = ((i_ * 8 + wv) * 64) + lane;                                                 \
    int p_ = c_ * 16;                                                                     \
    int r_ = p_ >> 7; int cb_ = (p_ & 127) ^ ((r_ & 7) << 4);                             \
    gl_lds16(Bt + (size_t)(n0 + r_) * K + (kt) + (cb_ >> 1),                              \
             &AB[bsel][8192 + ((i_ * 8 + wv) * 64) * 8]);                                 \
  }                                                                                       \
} while(0)

template<int OUT_BF16>
__global__ __launch_bounds__(512, 1) void gemm_bt2_k(
    const u16* __restrict__ A, const u16* __restrict__ Bt,
    void* __restrict__ Cout, int M, int N, int K)
{
  __shared__ __align__(16) u16 AB[2][24576];   // per buf: A[128][64] @0, B[256][64] @8192
  const int tid = threadIdx.x, lane = tid & 63, wv = tid >> 6;
  const int wr = wv >> 2, wc = wv & 3;          // 2 (M) x 4 (N) waves
  const int m0 = blockIdx.y * 128, n0 = blockIdx.x * 256;
  const int rq = lane >> 4, cl = lane & 15;
  const int NT = K >> 6;                        // 64-wide K tiles

  const f32x4 Z = {0.f, 0.f, 0.f, 0.f};
  f32x4 acc[4][4];
  #pragma unroll
  for (int m = 0; m < 4; m++)
    #pragma unroll
    for (int n = 0; n < 4; n++) acc[m][n] = Z;

  G2_STAGE(0, 0);
  G2_STAGE(64, 1);
  asm volatile("s_waitcnt vmcnt(6)");
  __builtin_amdgcn_sched_barrier(0);
  __builtin_amdgcn_s_barrier();

  int cur = 0;
  for (int t = 0; t < NT; t++){
    const char* As_ = (const char*)&AB[cur][0];
    const char* Bs_ = (const char*)&AB[cur][8192];

    #pragma unroll
    for (int ks = 0; ks < 2; ks++){
      const int kb = ks * 64 + rq * 16;
      bf16x8 a[4], b[4];
      #pragma unroll
      for (int m = 0; m < 4; m++){
        int r = wr * 64 + m * 16 + cl;
        a[m] = *(const bf16x8*)(As_ + r * 128 + (kb ^ ((r & 7) << 4)));
      }
      #pragma unroll
      for (int n = 0; n < 4; n++){
        int r = wc * 64 + n * 16 + cl;
        b[n] = *(const bf16x8*)(Bs_ + r * 128 + (kb ^ ((r & 7) << 4)));
      }
      __builtin_amdgcn_s_setprio(1);
      #pragma unroll
      for (int m = 0; m < 4; m++)
        #pragma unroll
        for (int n = 0; n < 4; n++)
          acc[m][n] = __builtin_amdgcn_mfma_f32_16x16x32_bf16(a[m], b[n], acc[m][n], 0, 0, 0);
      __builtin_amdgcn_s_setprio(0);
    }

    __builtin_amdgcn_sched_barrier(0);
    __builtin_amdgcn_s_barrier();              // every wave done READING buf[cur]

    if (t + 2 < NT){
      G2_STAGE((t + 2) * 64, cur);             // overwrite freed buffer
      asm volatile("s_waitcnt vmcnt(6)");      // tile t+1 landed; t+2 stays in flight
    } else {
      asm volatile("s_waitcnt vmcnt(0)");      // tail: drain remaining
    }
    __builtin_amdgcn_sched_barrier(0);
    __builtin_amdgcn_s_barrier();              // every wave's tile t+1 landed
    cur ^= 1;
  }

  #pragma unroll
  for (int m = 0; m < 4; m++){
    int gr0 = m0 + wr * 64 + m * 16 + rq * 4;
    #pragma unroll
    for (int n = 0; n < 4; n++){
      int gc = n0 + wc * 64 + n * 16 + cl;
      #pragma unroll
      for (int rr = 0; rr < 4; rr++){
        if (OUT_BF16) ((u16*)Cout)[(size_t)(gr0 + rr) * N + gc] = f2bf(acc[m][n][rr]);
        else          ((float*)Cout)[(size_t)(gr0 + rr) * N + gc] = acc[m][n][rr];
      }
    }
  }
}

// ---------------- flash attention v5 (r13-proven): counted-vmcnt pipeline ----------
// grid (bh=32 fast, pair p=0..15), 256 thr = 4 waves x 16 q-rows, 2 blocks/CU.
// qk buffer layout: row stride 4096, Q at col h*128, K at col 2048+h*128.

#define STAGE_K(jj, bsel) do {                                                            \
  _Pragma("unroll")                                                                       \
  for (int i_ = 0; i_ < 4; i_++){                                                         \
    int fb_ = (i_ * 4 + wv) * 64;                                                         \
    int p_  = (fb_ + lane) * 16;                                                          \
    int r_ = p_ >> 8; int cb_ = (p_ & 255) ^ ((r_ & 7) << 4);                             \
    gl_lds16(qk + (size_t)(b * LL + (jj) * 64 + r_) * QKN + 2048 + h * HDD + (cb_ >> 1),  \
             &Kb[bsel][fb_ * 8]);                                                         \
  }                                                                                       \
} while(0)

#define STAGE_V(jj) do {                                                                  \
  _Pragma("unroll")                                                                       \
  for (int i_ = 0; i_ < 4; i_++){                                                         \
    int fb_ = (i_ * 4 + wv) * 64;                                                         \
    int p_  = (fb_ + lane) * 16;                                                          \
    int r_ = p_ >> 7; int cb_ = (p_ & 127) ^ ((r_ & 7) << 4);                             \
    gl_lds16(vt + (size_t)(bh * HDD + r_) * LL + (jj) * 64 + (cb_ >> 1), &Vs[fb_ * 8]);   \
  }                                                                                       \
} while(0)

__global__ __launch_bounds__(256, 2) void attn_k(
    const u16* __restrict__ qk, const u16* __restrict__ vt,
    u16* __restrict__ aout)
{
  __shared__ __align__(16) u16 Kb[2][64 * 128];   // K tiles [64][128], 2x16KB
  __shared__ __align__(16) u16 Vs[128 * 64];      // V^T tile [128][64], 16KB
  __shared__ __align__(16) u16 Ps[4][1024];       // per-wave P tile 16x64, 8KB
  const int tid = threadIdx.x, lane = tid & 63, wv = tid >> 6;
  const int bh = blockIdx.x;                      // fast dim -> XCD = bh % 8
  const int pr = blockIdx.y;                      // pair index 0..15
  const int b = bh >> 4, h = bh & 15;
  const int rq = lane >> 4, cl = lane & 15;

  bf16x8 ones;
  #pragma unroll
  for (int i = 0; i < 8; i++) ones[i] = (__bf16)1.0f;
  const f32x4 Z = {0.f, 0.f, 0.f, 0.f};

  int cur = 0;
  STAGE_K(0, 0);                                  // phase-A tile 0
  asm volatile("s_waitcnt vmcnt(0)" ::: "memory");
  __builtin_amdgcn_sched_barrier(0);
  __builtin_amdgcn_s_barrier();

  #pragma unroll
  for (int ph = 0; ph < 2; ph++){
    const int qt = ph ? pr : (31 - pr);           // 64-row q-tile index
    const int nj = qt + 1;

    // Q fragments for this q-tile: wave rows qt*64 + wv*16 + cl
    bf16x8 qf[4];
    {
      const u16* qb = qk + (size_t)(b * LL + qt * 64 + wv * 16 + cl) * QKN + h * HDD + rq * 8;
      #pragma unroll
      for (int ks = 0; ks < 4; ks++) qf[ks] = *(const bf16x8*)(qb + ks * 32);
    }

    f32x4 acco[8], accl;
    float mst[4];
    #pragma unroll
    for (int n = 0; n < 8; n++) acco[n] = Z;
    accl = Z;
    #pragma unroll
    for (int rr = 0; rr < 4; rr++) mst[rr] = -INFINITY;

    for (int j = 0; j < nj; j++){
      const bool sn = (j + 1 < nj) || (ph == 0);  // will stage a next-K this iter
      STAGE_V(j);                                  // older in vm queue
      if (j + 1 < nj)      STAGE_K(j + 1, cur ^ 1);
      else if (ph == 0)    STAGE_K(0,     cur ^ 1);  // cross into phase B
      __builtin_amdgcn_sched_barrier(0);
      if (sn) asm volatile("s_waitcnt vmcnt(8)" ::: "memory");  // K(j) landed
      else    asm volatile("s_waitcnt vmcnt(4)" ::: "memory");
      __builtin_amdgcn_sched_barrier(0);
      __builtin_amdgcn_s_barrier();               // all waves' K(j) landed
      __builtin_amdgcn_sched_barrier(0);

      // S = Q K^T (16 q-rows x 64 kv per wave)
      f32x4 sv[4];
      {
        const char* KsC = (const char*)&Kb[cur][0];
        #pragma unroll
        for (int ct = 0; ct < 4; ct++) sv[ct] = Z;
        #pragma unroll
        for (int ks = 0; ks < 4; ks++){
          const int kb = ks * 64 + rq * 16;
          #pragma unroll
          for (int ct = 0; ct < 4; ct++){
            int r = ct * 16 + cl;
            bf16x8 bfr = *(const bf16x8*)(KsC + r * 256 + (kb ^ ((r & 7) << 4)));
            sv[ct] = __builtin_amdgcn_mfma_f32_16x16x32_bf16(qf[ks], bfr, sv[ct], 0, 0, 0);
          }
        }
      }

      // softmax (exp2 domain) + P write into own Ps slot (no barrier needed)
      {
        char* pbase = (char*)&Ps[wv][0];
        const bool msk = (j == qt);                 // diagonal tile only

        float p4[4][4], lmx[4];
        #pragma unroll
        for (int rr = 0; rr < 4; rr++) lmx[rr] = -1e30f;
        const int qg = qt * 64 + wv * 16 + rq * 4;
        #pragma unroll
        for (int ct = 0; ct < 4; ct++){
          int col = j * 64 + ct * 16 + cl;
          #pragma unroll
          for (int rr = 0; rr < 4; rr++){
            float v = sv[ct][rr];                   // already log2-domain
            if (msk && col > qg + rr) v = -1e30f;
            p4[ct][rr] = v;
            lmx[rr] = fmaxf(lmx[rr], v);
          }
        }
        // defer-max gate
        float need = -1e30f;
        #pragma unroll
        for (int rr = 0; rr < 4; rr++) need = fmaxf(need, lmx[rr] - mst[rr]);
        if (__any(need > THR2)){
          float mx[4];
          #pragma unroll
          for (int rr = 0; rr < 4; rr++) mx[rr] = lmx[rr];
          #pragma unroll
          for (int off = 1; off < 16; off <<= 1)
            #pragma unroll
            for (int rr = 0; rr < 4; rr++)
              mx[rr] = fmaxf(mx[rr], __shfl_xor(mx[rr], off, 64));
          #pragma unroll
          for (int rr = 0; rr < 4; rr++){
            float mn  = fmaxf(mst[rr], mx[rr]);
            float fsc = exp2_fast(mst[rr] - mn);
            mst[rr] = mn;
            accl[rr] *= fsc;
            #pragma unroll
            for (int n = 0; n < 8; n++) acco[n][rr] *= fsc;
          }
        }
        #pragma unroll
        for (int ct = 0; ct < 4; ct++)
          #pragma unroll
          for (int rr = 0; rr < 4; rr++){
            float e = exp2_fast(p4[ct][rr] - mst[rr]);
            int wr = rq * 4 + rr;
            *(u16*)(pbase + wr * 128 + (((ct * 16 + cl) * 2) ^ ((wr & 7) << 4))) = f2bf(e);
          }
      }

      __builtin_amdgcn_sched_barrier(0);
      if (sn) asm volatile("s_waitcnt vmcnt(4)" ::: "memory");  // V(j) landed
      else    asm volatile("s_waitcnt vmcnt(0)" ::: "memory");
      __builtin_amdgcn_sched_barrier(0);
      __builtin_amdgcn_s_barrier();               // all waves' V(j) landed
      __builtin_amdgcn_sched_barrier(0);

      // O += P V ; l += P 1
      {
        const char* VsC = (const char*)Vs;
        char* pbase = (char*)&Ps[wv][0];
        #pragma unroll
        for (int ks = 0; ks < 2; ks++){
          const int kvb = ks * 64 + rq * 16;
          bf16x8 pa = *(const bf16x8*)(pbase + cl * 128 + (kvb ^ ((cl & 7) << 4)));
          accl = __builtin_amdgcn_mfma_f32_16x16x32_bf16(pa, ones, accl, 0, 0, 0);
          #pragma unroll
          for (int n = 0; n < 8; n++){
            int r = n * 16 + cl;
            bf16x8 bfr = *(const bf16x8*)(VsC + r * 128 + (kvb ^ ((r & 7) << 4)));
            acco[n] = __builtin_amdgcn_mfma_f32_16x16x32_bf16(pa, bfr, acco[n], 0, 0, 0);
          }
        }
      }

      __builtin_amdgcn_sched_barrier(0);
      __builtin_amdgcn_s_barrier();               // all done reading Vs before next STAGE_V
      __builtin_amdgcn_sched_barrier(0);
      cur ^= 1;
    }

    // direct write-out
    #pragma unroll
    for (int rr = 0; rr < 4; rr++){
      float inv = 1.0f / accl[rr];
      size_t grow = (size_t)(b * LL + qt * 64 + wv * 16 + rq * 4 + rr);
      #pragma unroll
      for (int n = 0; n < 8; n++)
        aout[grow * HIDD + h * HDD + n * 16 + cl] = f2bf(acco[n][rr] * inv);
    }
  }
}

// ---------------- launcher ----------------

extern "C" void kernel_launch(void* const* d_in, const int* in_sizes, int n_in,
                              void* d_out, int out_size, void* d_ws, size_t ws_size,
                              hipStream_t stream)
{
  const float* x  = (const float*)d_in[0];
  // d_in[1] = mask (causal; applied analytically)
  const float* Wq = (const float*)d_in[2];
  const float* Wk = (const float*)d_in[3];
  const float* Wv = (const float*)d_in[4];
  const float* Wo = (const float*)d_in[5];
  float* out = (float*)d_out;

  if (ws_size < 120586240ull) return;  // need ~115 MB of scratch

  char* ws = (char*)d_ws;
  u16*    xb   = (u16*)(ws);                   // 4096x2048 bf16   (16 MB)
  u16*    Wt   = (u16*)(ws + 16777216ull);     // 6144x2048 bf16   (24 MB) = [Wq|Wk|Wv]^T
  u16*    Wot  = (u16*)(ws + 41943040ull);     // 2048x2048 bf16   ( 8 MB)
  u16*    qk   = (u16*)(ws + 50331648ull);     // 4096x4096 bf16   (32 MB) roped q|k
  u16*    vt   = (u16*)(ws + 83886080ull);     // 32x128x2048 bf16 (16 MB)
  u16*    aout = (u16*)(ws + 100663296ull);    // 4096x2048 bf16   (16 MB)
  float2* rtab = (float2*)(ws + 117440512ull); // 2048x64 float2   ( 1 MB)

  cvt_f32_bf16_k<<<2097152 / 256, 256, 0, stream>>>(x, xb, 2097152);
  rope_table_k<<<131072 / 256, 256, 0, stream>>>(rtab);
  transpose_cvt4_k<<<dim3(32, 32, 4), 256, 0, stream>>>(Wq, Wk, Wv, Wo, Wt, Wot);

  gemm_qkv_k<<<dim3(6144 / 128, 4096 / 128), 256, 0, stream>>>(xb, Wt, qk, vt, rtab, 4096, 6144, 2048);

  attn_k<<<dim3(32, 16), 256, 0, stream>>>(qk, vt, aout);

  gemm_bt2_k<0><<<dim3(2048 / 256, 4096 / 128), 512, 0, stream>>>(aout, Wot, out, 4096, 2048, 2048);
}

// Round 15
// 259.520 us; speedup vs baseline: 1.1902x; 1.0069x over previous
//
#include <hip/hip_runtime.h>
#include <math.h>

#define BB   2
#define LL   2048
#define HIDD 2048
#define NHH  16
#define HDD  128
#define QKN  4096   // q|k buffer row stride (v goes straight to vt)
#define THR2 11.5416f  // defer-max threshold, log2 domain (= 8 nats)
#define EST  136    // epilogue LDS row stride (u16): 272B rows, 16B-aligned

typedef unsigned short u16;
typedef float  f32x4 __attribute__((ext_vector_type(4)));
typedef __bf16 bf16x8 __attribute__((ext_vector_type(8)));

static __device__ __forceinline__ float exp2_fast(float x){
  return __builtin_amdgcn_exp2f(x);    // v_exp_f32 (native 2^x)
}
static __device__ __forceinline__ u16 f2bf(float x){
  unsigned u = __float_as_uint(x);
  return (u16)((u + 0x7fffu + ((u >> 16) & 1u)) >> 16);
}
static __device__ __forceinline__ float bf2f(u16 b){
  return __uint_as_float(((unsigned)b) << 16);
}
static __device__ __forceinline__ void gl_lds16(const void* g, void* l){
  __builtin_amdgcn_global_load_lds(
      (__attribute__((address_space(1))) void*)(void*)g,
      (__attribute__((address_space(3))) void*)l,
      16, 0, 0);
}

// ---------------- prep kernels ----------------

__global__ void cvt_f32_bf16_k(const float* __restrict__ src, u16* __restrict__ dst, int n4){
  int i = blockIdx.x * blockDim.x + threadIdx.x;
  if (i >= n4) return;
  float4 v = ((const float4*)src)[i];
  ushort4 o;
  o.x = f2bf(v.x); o.y = f2bf(v.y); o.z = f2bf(v.z); o.w = f2bf(v.w);
  ((ushort4*)dst)[i] = o;
}

// cos/sin table: tab[l*64+d] = (cos(th), sin(th)), th = (l/4)*exp(-d*ln(1e5)/64)
__global__ void rope_table_k(float2* __restrict__ tab){
  int idx = blockIdx.x * blockDim.x + threadIdx.x;   // 2048*64
  int l = idx >> 6, d = idx & 63;
  float fr = __expf(-(float)d * 0.17988946f);
  float th = (float)l * 0.25f * fr;
  float s, c;
  sincosf(th, &s, &c);
  tab[idx] = make_float2(c, s);
}

// fused 4x (2048^2 f32 -> transposed bf16). grid (32,32,4), 256 thr, 64x64 tiles.
__global__ __launch_bounds__(256) void transpose_cvt4_k(
    const float* __restrict__ Wq, const float* __restrict__ Wk,
    const float* __restrict__ Wv, const float* __restrict__ Wo,
    u16* __restrict__ Wt, u16* __restrict__ Wot)
{
  __shared__ u16 t[64][66];
  const int z = blockIdx.z;
  const float* src = (z == 0) ? Wq : (z == 1) ? Wk : (z == 2) ? Wv : Wo;
  u16* dst = (z == 3) ? Wot : (Wt + (size_t)z * 2048 * 2048);
  const int c0 = blockIdx.x * 64, r0 = blockIdx.y * 64;
  const int tid = threadIdx.x;

  #pragma unroll
  for (int i = 0; i < 4; i++){
    int r  = i * 16 + (tid >> 4);
    int c4 = (tid & 15) * 4;
    float4 v = *(const float4*)&src[(size_t)(r0 + r) * 2048 + c0 + c4];
    t[c4 + 0][r] = f2bf(v.x);
    t[c4 + 1][r] = f2bf(v.y);
    t[c4 + 2][r] = f2bf(v.z);
    t[c4 + 3][r] = f2bf(v.w);
  }
  __syncthreads();
  #pragma unroll
  for (int i = 0; i < 2; i++){
    int c  = i * 32 + (tid >> 3);
    int rs = (tid & 7) * 8;
    const unsigned* p = (const unsigned*)&t[c][rs];   // 4B-aligned
    unsigned w0 = p[0], w1 = p[1], w2 = p[2], w3 = p[3];
    u16* d = &dst[(size_t)(c0 + c) * 2048 + r0 + rs];
    ((unsigned*)d)[0] = w0; ((unsigned*)d)[1] = w1;
    ((unsigned*)d)[2] = w2; ((unsigned*)d)[3] = w3;
  }
}

// ---------------- GEMM 128x128 with fused RoPE/V^T epilogue (gemm1) ----------------
// K-loop identical to the proven 119us kernel. Epilogue: stage acc->LDS bf16
// (stride EST=136 u16 -> 16B-aligned rows, 2-way banks), then
//  sec 0/1 (q/k): rope via table with VECTOR LDS reads (ds_read_b128), write qk.
//  sec 2   (v)  : write transposed into vt ([bh][d][l], 128B contiguous/thread).

__global__ __launch_bounds__(256) void gemm_qkv_k(
    const u16* __restrict__ A, const u16* __restrict__ Bt,
    u16* __restrict__ qk, u16* __restrict__ vt,
    const float2* __restrict__ rtab, int M, int N, int K)
{
  __shared__ __align__(16) u16 SH[17408];      // K-loop: As=SH[0..8191], Bs=SH[8192..16383]
  u16* As = SH;
  u16* Bs = SH + 8192;
  const int tid = threadIdx.x, lane = tid & 63, wv = tid >> 6;
  const int wr = wv >> 1, wc = wv & 1;
  const int m0 = blockIdx.y * 128, n0 = blockIdx.x * 128;
  const int rq = lane >> 4, cl = lane & 15;

  const f32x4 Z = {0.f, 0.f, 0.f, 0.f};
  f32x4 acc[4][4];
  #pragma unroll
  for (int m = 0; m < 4; m++)
    #pragma unroll
    for (int n = 0; n < 4; n++) acc[m][n] = Z;

  for (int kt = 0; kt < K; kt += 64){
    #pragma unroll
    for (int i = 0; i < 4; i++){
      int fb = (i * 4 + wv) * 64;          // wave-uniform 16B-chunk base
      int p  = (fb + lane) * 16;           // this lane's physical LDS byte
      int r  = p >> 7;                     // tile row (128B rows)
      int cbs = (p & 127) ^ ((r & 7) << 4);
      gl_lds16(A  + (size_t)(m0 + r) * K + kt + (cbs >> 1), &As[fb * 8]);
      gl_lds16(Bt + (size_t)(n0 + r) * K + kt + (cbs >> 1), &Bs[fb * 8]);
    }
    __syncthreads();
    #pragma unroll
    for (int ks = 0; ks < 2; ks++){
      const int kb = ks * 64 + rq * 16;    // k byte offset in row
      bf16x8 a[4], b[4];
      #pragma unroll
      for (int m = 0; m < 4; m++){
        int r = wr * 64 + m * 16 + cl;
        a[m] = *(const bf16x8*)((const char*)As + r * 128 + (kb ^ ((r & 7) << 4)));
      }
      #pragma unroll
      for (int n = 0; n < 4; n++){
        int r = wc * 64 + n * 16 + cl;
        b[n] = *(const bf16x8*)((const char*)Bs + r * 128 + (kb ^ ((r & 7) << 4)));
      }
      #pragma unroll
      for (int m = 0; m < 4; m++)
        #pragma unroll
        for (int n = 0; n < 4; n++)
          acc[m][n] = __builtin_amdgcn_mfma_f32_16x16x32_bf16(a[m], b[n], acc[m][n], 0, 0, 0);
    }
    __syncthreads();
  }

  // ---- fused epilogue ----
  const int hd  = n0 >> 7;       // head-column 0..47
  const int sec = hd >> 4;       // 0=q, 1=k, 2=v
  const int hh  = hd & 15;

  // stage acc -> LDS bf16, stride EST (16B-aligned rows)
  #pragma unroll
  for (int m = 0; m < 4; m++){
    int gr0 = wr * 64 + m * 16 + rq * 4;
    #pragma unroll
    for (int n = 0; n < 4; n++){
      int gc = wc * 64 + n * 16 + cl;
      #pragma unroll
      for (int rr = 0; rr < 4; rr++)
        SH[(gr0 + rr) * EST + gc] = f2bf(acc[m][n][rr]);
    }
  }
  __syncthreads();

  if (sec < 2){
    // rope: thread t -> row r = t>>1, d in [dbase, dbase+32); vector LDS reads
    const float fsc = (sec == 0) ? 0.12753375f : 1.0f;   // q: 1/sqrt(128)*log2e
    const int r = tid >> 1, dbase = (tid & 1) * 32;
    const int l = (m0 + r) & (LL - 1);
    const float2* tab = rtab + l * 64 + dbase;
    const u16* srow = &SH[r * EST];
    u16* orow = qk + (size_t)(m0 + r) * QKN + hd * 128;
    #pragma unroll
    for (int g = 0; g < 4; g++){
      bf16x8 x1v = *(const bf16x8*)(srow + dbase + g * 8);
      bf16x8 x2v = *(const bf16x8*)(srow + dbase + 64 + g * 8);
      bf16x8 o1, o2;
      #pragma unroll
      for (int i = 0; i < 8; i++){
        float2 cs = tab[g * 8 + i];
        float x1 = (float)x1v[i], x2 = (float)x2v[i];
        o1[i] = (__bf16)((x1 * cs.x - x2 * cs.y) * fsc);
        o2[i] = (__bf16)((x1 * cs.y + x2 * cs.x) * fsc);
      }
      *(bf16x8*)(orow + dbase + g * 8)      = o1;
      *(bf16x8*)(orow + dbase + 64 + g * 8) = o2;
    }
  } else {
    // v: thread t -> d = t>>1, l-half l0 = (t&1)*64; write vt[bh][d][l] contiguous
    const int d = tid >> 1, l0 = (tid & 1) * 64;
    const int bh = ((m0 >> 11) << 4) + hh;
    u16* vrow = vt + ((size_t)bh * HDD + d) * LL + (m0 & (LL - 1)) + l0;
    #pragma unroll
    for (int g = 0; g < 8; g++){
      bf16x8 o;
      #pragma unroll
      for (int i = 0; i < 8; i++)
        o[i] = *(__bf16*)&SH[(l0 + g * 8 + i) * EST + d];
      *(bf16x8*)(vrow + g * 8) = o;
    }
  }
}

// ---------------- GEMM 128x256 counted-vmcnt (proven for gemm2) ----------------

#define G2_STAGE(kt, bsel) do {                                                           \
  _Pragma("unroll")                                                                       \
  for (int i_ = 0; i_ < 2; i_++){     /* A: 128x64 = 1024 chunks */                       \
    int c_ = ((i_ * 8 + wv) * 64) + lane;                                                 \
    int p_ = c_ * 16;                                                                     \
    int r_ = p_ >> 7; int cb_ = (p_ & 127) ^ ((r_ & 7) << 4);                             \
    gl_lds16(A + (size_t)(m0 + r_) * K + (kt) + (cb_ >> 1),                               \
             &AB[bsel][((i_ * 8 + wv) * 64) * 8]);                                        \
  }                                                                                       \
  _Pragma("unroll")                                                                       \
  for (int i_ = 0; i_ < 4; i_++){     /* B: 256x64 = 2048 chunks */                       \
    int c_ = ((i_ * 8 + wv) * 64) + lane;                                                 \
    int p_ = c_ * 16;                                                                     \
    int r_ = p_ >> 7; int cb_ = (p_ & 127) ^ ((r_ & 7) << 4);                             \
    gl_lds16(Bt + (size_t)(n0 + r_) * K + (kt) + (cb_ >> 1),                              \
             &AB[bsel][8192 + ((i_ * 8 + wv) * 64) * 8]);                                 \
  }                                                                                       \
} while(0)

template<int OUT_BF16>
__global__ __launch_bounds__(512, 1) void gemm_bt2_k(
    const u16* __restrict__ A, const u16* __restrict__ Bt,
    void* __restrict__ Cout, int M, int N, int K)
{
  __shared__ __align__(16) u16 AB[2][24576];   // per buf: A[128][64] @0, B[256][64] @8192
  const int tid = threadIdx.x, lane = tid & 63, wv = tid >> 6;
  const int wr = wv >> 2, wc = wv & 3;          // 2 (M) x 4 (N) waves
  const int m0 = blockIdx.y * 128, n0 = blockIdx.x * 256;
  const int rq = lane >> 4, cl = lane & 15;
  const int NT = K >> 6;                        // 64-wide K tiles

  const f32x4 Z = {0.f, 0.f, 0.f, 0.f};
  f32x4 acc[4][4];
  #pragma unroll
  for (int m = 0; m < 4; m++)
    #pragma unroll
    for (int n = 0; n < 4; n++) acc[m][n] = Z;

  G2_STAGE(0, 0);
  G2_STAGE(64, 1);
  asm volatile("s_waitcnt vmcnt(6)");
  __builtin_amdgcn_sched_barrier(0);
  __builtin_amdgcn_s_barrier();

  int cur = 0;
  for (int t = 0; t < NT; t++){
    const char* As_ = (const char*)&AB[cur][0];
    const char* Bs_ = (const char*)&AB[cur][8192];

    #pragma unroll
    for (int ks = 0; ks < 2; ks++){
      const int kb = ks * 64 + rq * 16;
      bf16x8 a[4], b[4];
      #pragma unroll
      for (int m = 0; m < 4; m++){
        int r = wr * 64 + m * 16 + cl;
        a[m] = *(const bf16x8*)(As_ + r * 128 + (kb ^ ((r & 7) << 4)));
      }
      #pragma unroll
      for (int n = 0; n < 4; n++){
        int r = wc * 64 + n * 16 + cl;
        b[n] = *(const bf16x8*)(Bs_ + r * 128 + (kb ^ ((r & 7) << 4)));
      }
      __builtin_amdgcn_s_setprio(1);
      #pragma unroll
      for (int m = 0; m < 4; m++)
        #pragma unroll
        for (int n = 0; n < 4; n++)
          acc[m][n] = __builtin_amdgcn_mfma_f32_16x16x32_bf16(a[m], b[n], acc[m][n], 0, 0, 0);
      __builtin_amdgcn_s_setprio(0);
    }

    __builtin_amdgcn_sched_barrier(0);
    __builtin_amdgcn_s_barrier();              // every wave done READING buf[cur]

    if (t + 2 < NT){
      G2_STAGE((t + 2) * 64, cur);             // overwrite freed buffer
      asm volatile("s_waitcnt vmcnt(6)");      // tile t+1 landed; t+2 stays in flight
    } else {
      asm volatile("s_waitcnt vmcnt(0)");      // tail: drain remaining
    }
    __builtin_amdgcn_sched_barrier(0);
    __builtin_amdgcn_s_barrier();              // every wave's tile t+1 landed
    cur ^= 1;
  }

  #pragma unroll
  for (int m = 0; m < 4; m++){
    int gr0 = m0 + wr * 64 + m * 16 + rq * 4;
    #pragma unroll
    for (int n = 0; n < 4; n++){
      int gc = n0 + wc * 64 + n * 16 + cl;
      #pragma unroll
      for (int rr = 0; rr < 4; rr++){
        if (OUT_BF16) ((u16*)Cout)[(size_t)(gr0 + rr) * N + gc] = f2bf(acc[m][n][rr]);
        else          ((float*)Cout)[(size_t)(gr0 + rr) * N + gc] = acc[m][n][rr];
      }
    }
  }
}

// ---------------- flash attention v6: deep K+V prefetch, 2 barriers/iter ----------
// grid (bh=32 fast, pair p=0..15), 256 thr = 4 waves x 16 q-rows, 2 blocks/CU.
// K dbuf 32KB + V dbuf 32KB + P 8KB = 72KB (144KB/CU). Per iter: stage V(j+1)+
// K(j+1) into cur^1 -> vmcnt(8) (current tile fully landed; next 8 in flight)
// -> barrier -> QK -> softmax/P -> PV -> barrier. One wait, two barriers.

#define STAGE_K(jj, bsel) do {                                                            \
  _Pragma("unroll")                                                                       \
  for (int i_ = 0; i_ < 4; i_++){                                                         \
    int fb_ = (i_ * 4 + wv) * 64;                                                         \
    int p_  = (fb_ + lane) * 16;                                                          \
    int r_ = p_ >> 8; int cb_ = (p_ & 255) ^ ((r_ & 7) << 4);                             \
    gl_lds16(qk + (size_t)(b * LL + (jj) * 64 + r_) * QKN + 2048 + h * HDD + (cb_ >> 1),  \
             &Kb[bsel][fb_ * 8]);                                                         \
  }                                                                                       \
} while(0)

#define STAGE_V(jj, bsel) do {                                                            \
  _Pragma("unroll")                                                                       \
  for (int i_ = 0; i_ < 4; i_++){                                                         \
    int fb_ = (i_ * 4 + wv) * 64;                                                         \
    int p_  = (fb_ + lane) * 16;                                                          \
    int r_ = p_ >> 7; int cb_ = (p_ & 127) ^ ((r_ & 7) << 4);                             \
    gl_lds16(vt + (size_t)(bh * HDD + r_) * LL + (jj) * 64 + (cb_ >> 1),                  \
             &Vb[bsel][fb_ * 8]);                                                         \
  }                                                                                       \
} while(0)

__global__ __launch_bounds__(256, 2) void attn_k(
    const u16* __restrict__ qk, const u16* __restrict__ vt,
    u16* __restrict__ aout)
{
  __shared__ __align__(16) u16 Kb[2][64 * 128];   // K tiles, 2x16KB
  __shared__ __align__(16) u16 Vb[2][128 * 64];   // V^T tiles, 2x16KB
  __shared__ __align__(16) u16 Ps[4][1024];       // per-wave P tile 16x64, 8KB
  const int tid = threadIdx.x, lane = tid & 63, wv = tid >> 6;
  const int bh = blockIdx.x;                      // fast dim -> XCD = bh % 8
  const int pr = blockIdx.y;                      // pair index 0..15
  const int b = bh >> 4, h = bh & 15;
  const int rq = lane >> 4, cl = lane & 15;

  bf16x8 ones;
  #pragma unroll
  for (int i = 0; i < 8; i++) ones[i] = (__bf16)1.0f;
  const f32x4 Z = {0.f, 0.f, 0.f, 0.f};

  int cur = 0;
  STAGE_V(0, 0);                                  // phase-A tile 0 (V older in queue)
  STAGE_K(0, 0);

  #pragma unroll
  for (int ph = 0; ph < 2; ph++){
    const int qt = ph ? pr : (31 - pr);           // 64-row q-tile index
    const int nj = qt + 1;

    // Q fragments for this q-tile: wave rows qt*64 + wv*16 + cl
    bf16x8 qf[4];
    {
      const u16* qb = qk + (size_t)(b * LL + qt * 64 + wv * 16 + cl) * QKN + h * HDD + rq * 8;
      #pragma unroll
      for (int ks = 0; ks < 4; ks++) qf[ks] = *(const bf16x8*)(qb + ks * 32);
    }

    f32x4 acco[8], accl;
    float mst[4];
    #pragma unroll
    for (int n = 0; n < 8; n++) acco[n] = Z;
    accl = Z;
    #pragma unroll
    for (int rr = 0; rr < 4; rr++) mst[rr] = -INFINITY;

    for (int j = 0; j < nj; j++){
      const bool sn = (j + 1 < nj) || (ph == 0);  // stages a next tile this iter
      if (j + 1 < nj){      STAGE_V(j + 1, cur ^ 1); STAGE_K(j + 1, cur ^ 1); }
      else if (ph == 0){    STAGE_V(0,     cur ^ 1); STAGE_K(0,     cur ^ 1); }
      __builtin_amdgcn_sched_barrier(0);
      if (sn) asm volatile("s_waitcnt vmcnt(8)" ::: "memory");  // tile j fully landed
      else    asm volatile("s_waitcnt vmcnt(0)" ::: "memory");
      __builtin_amdgcn_sched_barrier(0);
      __builtin_amdgcn_s_barrier();               // all waves' K(j),V(j) landed
      __builtin_amdgcn_sched_barrier(0);

      // S = Q K^T (16 q-rows x 64 kv per wave)
      f32x4 sv[4];
      {
        const char* KsC = (const char*)&Kb[cur][0];
        #pragma unroll
        for (int ct = 0; ct < 4; ct++) sv[ct] = Z;
        #pragma unroll
        for (int ks = 0; ks < 4; ks++){
          const int kb = ks * 64 + rq * 16;
          #pragma unroll
          for (int ct = 0; ct < 4; ct++){
            int r = ct * 16 + cl;
            bf16x8 bfr = *(const bf16x8*)(KsC + r * 256 + (kb ^ ((r & 7) << 4)));
            sv[ct] = __builtin_amdgcn_mfma_f32_16x16x32_bf16(qf[ks], bfr, sv[ct], 0, 0, 0);
          }
        }
      }

      // softmax (exp2 domain) + P write into own Ps slot (in-wave RAW ordering)
      {
        char* pbase = (char*)&Ps[wv][0];
        const bool msk = (j == qt);                 // diagonal tile only

        float p4[4][4], lmx[4];
        #pragma unroll
        for (int rr = 0; rr < 4; rr++) lmx[rr] = -1e30f;
        const int qg = qt * 64 + wv * 16 + rq * 4;
        #pragma unroll
        for (int ct = 0; ct < 4; ct++){
          int col = j * 64 + ct * 16 + cl;
          #pragma unroll
          for (int rr = 0; rr < 4; rr++){
            float v = sv[ct][rr];                   // already log2-domain
            if (msk && col > qg + rr) v = -1e30f;
            p4[ct][rr] = v;
            lmx[rr] = fmaxf(lmx[rr], v);
          }
        }
        // defer-max gate
        float need = -1e30f;
        #pragma unroll
        for (int rr = 0; rr < 4; rr++) need = fmaxf(need, lmx[rr] - mst[rr]);
        if (__any(need > THR2)){
          float mx[4];
          #pragma unroll
          for (int rr = 0; rr < 4; rr++) mx[rr] = lmx[rr];
          #pragma unroll
          for (int off = 1; off < 16; off <<= 1)
            #pragma unroll
            for (int rr = 0; rr < 4; rr++)
              mx[rr] = fmaxf(mx[rr], __shfl_xor(mx[rr], off, 64));
          #pragma unroll
          for (int rr = 0; rr < 4; rr++){
            float mn  = fmaxf(mst[rr], mx[rr]);
            float fsc = exp2_fast(mst[rr] - mn);
            mst[rr] = mn;
            accl[rr] *= fsc;
            #pragma unroll
            for (int n = 0; n < 8; n++) acco[n][rr] *= fsc;
          }
        }
        #pragma unroll
        for (int ct = 0; ct < 4; ct++)
          #pragma unroll
          for (int rr = 0; rr < 4; rr++){
            float e = exp2_fast(p4[ct][rr] - mst[rr]);
            int wr = rq * 4 + rr;
            *(u16*)(pbase + wr * 128 + (((ct * 16 + cl) * 2) ^ ((wr & 7) << 4))) = f2bf(e);
          }
      }

      // O += P V ; l += P 1  (V already resident; no mid-iter wait)
      {
        const char* VsC = (const char*)&Vb[cur][0];
        char* pbase = (char*)&Ps[wv][0];
        #pragma unroll
        for (int ks = 0; ks < 2; ks++){
          const int kvb = ks * 64 + rq * 16;
          bf16x8 pa = *(const bf16x8*)(pbase + cl * 128 + (kvb ^ ((cl & 7) << 4)));
          accl = __builtin_amdgcn_mfma_f32_16x16x32_bf16(pa, ones, accl, 0, 0, 0);
          #pragma unroll
          for (int n = 0; n < 8; n++){
            int r = n * 16 + cl;
            bf16x8 bfr = *(const bf16x8*)(VsC + r * 128 + (kvb ^ ((r & 7) << 4)));
            acco[n] = __builtin_amdgcn_mfma_f32_16x16x32_bf16(pa, bfr, acco[n], 0, 0, 0);
          }
        }
      }

      __builtin_amdgcn_sched_barrier(0);
      __builtin_amdgcn_s_barrier();               // reads of buf[cur] done before its overwrite
      __builtin_amdgcn_sched_barrier(0);
      cur ^= 1;
    }

    // direct write-out
    #pragma unroll
    for (int rr = 0; rr < 4; rr++){
      float inv = 1.0f / accl[rr];
      size_t grow = (size_t)(b * LL + qt * 64 + wv * 16 + rq * 4 + rr);
      #pragma unroll
      for (int n = 0; n < 8; n++)
        aout[grow * HIDD + h * HDD + n * 16 + cl] = f2bf(acco[n][rr] * inv);
    }
  }
}

// ---------------- launcher ----------------

extern "C" void kernel_launch(void* const* d_in, const int* in_sizes, int n_in,
                              void* d_out, int out_size, void* d_ws, size_t ws_size,
                              hipStream_t stream)
{
  const float* x  = (const float*)d_in[0];
  // d_in[1] = mask (causal; applied analytically)
  const float* Wq = (const float*)d_in[2];
  const float* Wk = (const float*)d_in[3];
  const float* Wv = (const float*)d_in[4];
  const float* Wo = (const float*)d_in[5];
  float* out = (float*)d_out;

  if (ws_size < 120586240ull) return;  // need ~115 MB of scratch

  char* ws = (char*)d_ws;
  u16*    xb   = (u16*)(ws);                   // 4096x2048 bf16   (16 MB)
  u16*    Wt   = (u16*)(ws + 16777216ull);     // 6144x2048 bf16   (24 MB) = [Wq|Wk|Wv]^T
  u16*    Wot  = (u16*)(ws + 41943040ull);     // 2048x2048 bf16   ( 8 MB)
  u16*    qk   = (u16*)(ws + 50331648ull);     // 4096x4096 bf16   (32 MB) roped q|k
  u16*    vt   = (u16*)(ws + 83886080ull);     // 32x128x2048 bf16 (16 MB)
  u16*    aout = (u16*)(ws + 100663296ull);    // 4096x2048 bf16   (16 MB)
  float2* rtab = (float2*)(ws + 117440512ull); // 2048x64 float2   ( 1 MB)

  cvt_f32_bf16_k<<<2097152 / 256, 256, 0, stream>>>(x, xb, 2097152);
  rope_table_k<<<131072 / 256, 256, 0, stream>>>(rtab);
  transpose_cvt4_k<<<dim3(32, 32, 4), 256, 0, stream>>>(Wq, Wk, Wv, Wo, Wt, Wot);

  gemm_qkv_k<<<dim3(6144 / 128, 4096 / 128), 256, 0, stream>>>(xb, Wt, qk, vt, rtab, 4096, 6144, 2048);

  attn_k<<<dim3(32, 16), 256, 0, stream>>>(qk, vt, aout);

  gemm_bt2_k<0><<<dim3(2048 / 256, 4096 / 128), 512, 0, stream>>>(aout, Wot, out, 4096, 2048, 2048);
}

// Round 17
// 256.051 us; speedup vs baseline: 1.2064x; 1.0135x over previous
//
#include <hip/hip_runtime.h>
#include <math.h>

#define BB   2
#define LL   2048
#define HIDD 2048
#define NHH  16
#define HDD  128
#define QKN  4096   // q|k buffer row stride
#define THR2 11.5416f  // defer-max threshold, log2 domain (= 8 nats)
#define EST2 264    // 256-wide epilogue LDS row stride (u16): 528B rows, 16B-aligned

typedef unsigned short u16;
typedef float  f32x4 __attribute__((ext_vector_type(4)));
typedef __bf16 bf16x8 __attribute__((ext_vector_type(8)));

static __device__ __forceinline__ float exp2_fast(float x){
  return __builtin_amdgcn_exp2f(x);    // v_exp_f32 (native 2^x)
}
static __device__ __forceinline__ u16 f2bf(float x){
  unsigned u = __float_as_uint(x);
  return (u16)((u + 0x7fffu + ((u >> 16) & 1u)) >> 16);
}
static __device__ __forceinline__ float bf2f(u16 b){
  return __uint_as_float(((unsigned)b) << 16);
}
static __device__ __forceinline__ void gl_lds16(const void* g, void* l){
  __builtin_amdgcn_global_load_lds(
      (__attribute__((address_space(1))) void*)(void*)g,
      (__attribute__((address_space(3))) void*)l,
      16, 0, 0);
}

// ---------------- prep kernels ----------------

__global__ void cvt_f32_bf16_k(const float* __restrict__ src, u16* __restrict__ dst, int n4){
  int i = blockIdx.x * blockDim.x + threadIdx.x;
  if (i >= n4) return;
  float4 v = ((const float4*)src)[i];
  ushort4 o;
  o.x = f2bf(v.x); o.y = f2bf(v.y); o.z = f2bf(v.z); o.w = f2bf(v.w);
  ((ushort4*)dst)[i] = o;
}

// cos/sin table: tab[l*64+d] = (cos(th), sin(th)), th = (l/4)*exp(-d*ln(1e5)/64)
__global__ void rope_table_k(float2* __restrict__ tab){
  int idx = blockIdx.x * blockDim.x + threadIdx.x;   // 2048*64
  int l = idx >> 6, d = idx & 63;
  float fr = __expf(-(float)d * 0.17988946f);
  float th = (float)l * 0.25f * fr;
  float s, c;
  sincosf(th, &s, &c);
  tab[idx] = make_float2(c, s);
}

// fused 4x (2048^2 f32 -> transposed bf16). grid (32,32,4), 256 thr, 64x64 tiles.
__global__ __launch_bounds__(256) void transpose_cvt4_k(
    const float* __restrict__ Wq, const float* __restrict__ Wk,
    const float* __restrict__ Wv, const float* __restrict__ Wo,
    u16* __restrict__ Wt, u16* __restrict__ Wot)
{
  __shared__ u16 t[64][66];
  const int z = blockIdx.z;
  const float* src = (z == 0) ? Wq : (z == 1) ? Wk : (z == 2) ? Wv : Wo;
  u16* dst = (z == 3) ? Wot : (Wt + (size_t)z * 2048 * 2048);
  const int c0 = blockIdx.x * 64, r0 = blockIdx.y * 64;
  const int tid = threadIdx.x;

  #pragma unroll
  for (int i = 0; i < 4; i++){
    int r  = i * 16 + (tid >> 4);
    int c4 = (tid & 15) * 4;
    float4 v = *(const float4*)&src[(size_t)(r0 + r) * 2048 + c0 + c4];
    t[c4 + 0][r] = f2bf(v.x);
    t[c4 + 1][r] = f2bf(v.y);
    t[c4 + 2][r] = f2bf(v.z);
    t[c4 + 3][r] = f2bf(v.w);
  }
  __syncthreads();
  #pragma unroll
  for (int i = 0; i < 2; i++){
    int c  = i * 32 + (tid >> 3);
    int rs = (tid & 7) * 8;
    const unsigned* p = (const unsigned*)&t[c][rs];   // 4B-aligned
    unsigned w0 = p[0], w1 = p[1], w2 = p[2], w3 = p[3];
    u16* d = &dst[(size_t)(c0 + c) * 2048 + r0 + rs];
    ((unsigned*)d)[0] = w0; ((unsigned*)d)[1] = w1;
    ((unsigned*)d)[2] = w2; ((unsigned*)d)[3] = w3;
  }
}

// ---------------- GEMM1: 256x256 tile, 4-phase quadrant schedule, fused epilogue ------
// 8 waves (2M x 4N). Per phase: block C-quadrant (i,j) 128x128; all waves read only
// A-half i + B-half j. Stage ledger: ph0: A1(t+1), ph1: B1(t+1), ph2: A0(t+2),
// ph3: B0(t+2) — each stage targets a region whose last reader finished before this
// phase's entry barrier. Boundary wait vmcnt(4); vmcnt(0) at last tile.
// LDS map (bytes): A bufs [0, 65536) (buf X at X*32768; halves at +0/+16384),
//                  B bufs [65536, 131072) (same structure).

#define STG_HALF(base_u16, src, rowbase, kt_) do {                                        \
  _Pragma("unroll")                                                                       \
  for (int i_ = 0; i_ < 2; i_++){                                                         \
    int cb0_ = i_ * 512 + wv * 64;             /* wave-uniform chunk base */              \
    int c_   = cb0_ + lane;                                                               \
    int r_   = c_ >> 3;                        /* row 0..127 within half */               \
    int cb_  = ((c_ & 7) << 4) ^ ((r_ & 7) << 4);                                         \
    gl_lds16((src) + (size_t)((rowbase) + r_) * K + (kt_) + (cb_ >> 1),                   \
             &SH[(base_u16) + cb0_ * 8]);                                                 \
  }                                                                                       \
} while(0)

__global__ __launch_bounds__(512, 1) void gemm_qkv256_k(
    const u16* __restrict__ A, const u16* __restrict__ Bt,
    u16* __restrict__ qk, u16* __restrict__ vt,
    const float2* __restrict__ rtab, int K)
{
  __shared__ __align__(16) u16 SH[65536];   // 128KB
  const int tid = threadIdx.x, lane = tid & 63, wv = tid >> 6;
  const int wsr = wv >> 2, wsc = wv & 3;     // 2(M) x 4(N) wave grid
  const int m0 = blockIdx.y * 256, n0 = blockIdx.x * 256;
  const int rq = lane >> 4, cl = lane & 15;
  const int NT = K >> 6;                     // 32

  const f32x4 Z = {0.f, 0.f, 0.f, 0.f};
  f32x4 acc[2][2][4][2];                     // [i][j][mf][nf]
  #pragma unroll
  for (int i = 0; i < 2; i++)
    #pragma unroll
    for (int j = 0; j < 2; j++)
      #pragma unroll
      for (int mf = 0; mf < 4; mf++)
        #pragma unroll
        for (int nf = 0; nf < 2; nf++) acc[i][j][mf][nf] = Z;

  // prologue stages (order matters for vmcnt ledger):
  STG_HALF(0,                 A,  m0 + 0,   0);    // A0(0)
  STG_HALF(32768,             Bt, n0 + 0,   0);    // B0(0)
  STG_HALF(8192,              A,  m0 + 128, 0);    // A1(0)
  STG_HALF(32768 + 8192,      Bt, n0 + 128, 0);    // B1(0)
  STG_HALF(16384,             A,  m0 + 0,   64);   // A0(1)
  STG_HALF(32768 + 16384,     Bt, n0 + 0,   64);   // B0(1)

  for (int t = 0; t < NT; t++){
    const int X = t & 1;
    const char* Ab = (const char*)SH + X * 32768;
    const char* Bb = (const char*)SH + 65536 + X * 32768;   // FIXED: B region starts at byte 65536
    bf16x8 af[4][2], bfb[2][2];

    // ---- ph0: quadrant (0,0) ----
    __builtin_amdgcn_sched_barrier(0);
    if (t == NT - 1) asm volatile("s_waitcnt vmcnt(0)" ::: "memory");
    else             asm volatile("s_waitcnt vmcnt(4)" ::: "memory");
    __builtin_amdgcn_sched_barrier(0);
    __builtin_amdgcn_s_barrier();
    __builtin_amdgcn_sched_barrier(0);
    #pragma unroll
    for (int mf = 0; mf < 4; mf++){
      int gr = wsr * 64 + mf * 16 + cl;                      // i=0
      #pragma unroll
      for (int ks = 0; ks < 2; ks++)
        af[mf][ks] = *(const bf16x8*)(Ab + gr * 128 + ((ks * 64 + rq * 16) ^ ((gr & 7) << 4)));
    }
    #pragma unroll
    for (int nf = 0; nf < 2; nf++){
      int gc = wsc * 32 + nf * 16 + cl;                      // j=0
      #pragma unroll
      for (int ks = 0; ks < 2; ks++)
        bfb[nf][ks] = *(const bf16x8*)(Bb + gc * 128 + ((ks * 64 + rq * 16) ^ ((gc & 7) << 4)));
    }
    if (t + 1 < NT) STG_HALF(((t + 1) & 1) * 16384 + 8192, A, m0 + 128, (t + 1) * 64);   // A1(t+1)
    __builtin_amdgcn_sched_barrier(0);
    asm volatile("s_waitcnt lgkmcnt(0)" ::: "memory");
    __builtin_amdgcn_sched_barrier(0);
    __builtin_amdgcn_s_setprio(1);
    #pragma unroll
    for (int mf = 0; mf < 4; mf++)
      #pragma unroll
      for (int nf = 0; nf < 2; nf++)
        #pragma unroll
        for (int ks = 0; ks < 2; ks++)
          acc[0][0][mf][nf] = __builtin_amdgcn_mfma_f32_16x16x32_bf16(af[mf][ks], bfb[nf][ks], acc[0][0][mf][nf], 0, 0, 0);
    __builtin_amdgcn_s_setprio(0);
    __builtin_amdgcn_sched_barrier(0);

    // ---- ph1: quadrant (0,1), reuse af ----
    __builtin_amdgcn_s_barrier();
    __builtin_amdgcn_sched_barrier(0);
    #pragma unroll
    for (int nf = 0; nf < 2; nf++){
      int gc = 128 + wsc * 32 + nf * 16 + cl;                // j=1
      #pragma unroll
      for (int ks = 0; ks < 2; ks++)
        bfb[nf][ks] = *(const bf16x8*)(Bb + gc * 128 + ((ks * 64 + rq * 16) ^ ((gc & 7) << 4)));
    }
    if (t + 1 < NT) STG_HALF(32768 + ((t + 1) & 1) * 16384 + 8192, Bt, n0 + 128, (t + 1) * 64); // B1(t+1)
    __builtin_amdgcn_sched_barrier(0);
    asm volatile("s_waitcnt lgkmcnt(0)" ::: "memory");
    __builtin_amdgcn_sched_barrier(0);
    __builtin_amdgcn_s_setprio(1);
    #pragma unroll
    for (int mf = 0; mf < 4; mf++)
      #pragma unroll
      for (int nf = 0; nf < 2; nf++)
        #pragma unroll
        for (int ks = 0; ks < 2; ks++)
          acc[0][1][mf][nf] = __builtin_amdgcn_mfma_f32_16x16x32_bf16(af[mf][ks], bfb[nf][ks], acc[0][1][mf][nf], 0, 0, 0);
    __builtin_amdgcn_s_setprio(0);
    __builtin_amdgcn_sched_barrier(0);

    // ---- ph2: quadrant (1,0) ----
    __builtin_amdgcn_s_barrier();
    __builtin_amdgcn_sched_barrier(0);
    #pragma unroll
    for (int mf = 0; mf < 4; mf++){
      int gr = 128 + wsr * 64 + mf * 16 + cl;                // i=1
      #pragma unroll
      for (int ks = 0; ks < 2; ks++)
        af[mf][ks] = *(const bf16x8*)(Ab + gr * 128 + ((ks * 64 + rq * 16) ^ ((gr & 7) << 4)));
    }
    #pragma unroll
    for (int nf = 0; nf < 2; nf++){
      int gc = wsc * 32 + nf * 16 + cl;                      // j=0 (re-read)
      #pragma unroll
      for (int ks = 0; ks < 2; ks++)
        bfb[nf][ks] = *(const bf16x8*)(Bb + gc * 128 + ((ks * 64 + rq * 16) ^ ((gc & 7) << 4)));
    }
    if (t + 2 < NT) STG_HALF((t & 1) * 16384, A, m0 + 0, (t + 2) * 64);                  // A0(t+2)
    __builtin_amdgcn_sched_barrier(0);
    asm volatile("s_waitcnt lgkmcnt(0)" ::: "memory");
    __builtin_amdgcn_sched_barrier(0);
    __builtin_amdgcn_s_setprio(1);
    #pragma unroll
    for (int mf = 0; mf < 4; mf++)
      #pragma unroll
      for (int nf = 0; nf < 2; nf++)
        #pragma unroll
        for (int ks = 0; ks < 2; ks++)
          acc[1][0][mf][nf] = __builtin_amdgcn_mfma_f32_16x16x32_bf16(af[mf][ks], bfb[nf][ks], acc[1][0][mf][nf], 0, 0, 0);
    __builtin_amdgcn_s_setprio(0);
    __builtin_amdgcn_sched_barrier(0);

    // ---- ph3: quadrant (1,1), reuse af ----
    __builtin_amdgcn_s_barrier();
    __builtin_amdgcn_sched_barrier(0);
    #pragma unroll
    for (int nf = 0; nf < 2; nf++){
      int gc = 128 + wsc * 32 + nf * 16 + cl;                // j=1
      #pragma unroll
      for (int ks = 0; ks < 2; ks++)
        bfb[nf][ks] = *(const bf16x8*)(Bb + gc * 128 + ((ks * 64 + rq * 16) ^ ((gc & 7) << 4)));
    }
    if (t + 2 < NT) STG_HALF(32768 + (t & 1) * 16384, Bt, n0 + 0, (t + 2) * 64);         // B0(t+2)
    __builtin_amdgcn_sched_barrier(0);
    asm volatile("s_waitcnt lgkmcnt(0)" ::: "memory");
    __builtin_amdgcn_sched_barrier(0);
    __builtin_amdgcn_s_setprio(1);
    #pragma unroll
    for (int mf = 0; mf < 4; mf++)
      #pragma unroll
      for (int nf = 0; nf < 2; nf++)
        #pragma unroll
        for (int ks = 0; ks < 2; ks++)
          acc[1][1][mf][nf] = __builtin_amdgcn_mfma_f32_16x16x32_bf16(af[mf][ks], bfb[nf][ks], acc[1][1][mf][nf], 0, 0, 0);
    __builtin_amdgcn_s_setprio(0);
    __builtin_amdgcn_sched_barrier(0);
  }

  // ---- fused epilogue: two row-half passes over the 256x256 tile ----
  const int sec = n0 >> 11;       // 0=q, 1=k, 2=v
  const int hd2 = n0 >> 7;        // first head-col of this tile (even)
  u16* ES = SH;

  #pragma unroll
  for (int ih = 0; ih < 2; ih++){
    __syncthreads();
    // stage this row-half's acc -> ES[128][EST2]
    #pragma unroll
    for (int j = 0; j < 2; j++)
      #pragma unroll
      for (int mf = 0; mf < 4; mf++){
        int er = wsr * 64 + mf * 16 + rq * 4;
        #pragma unroll
        for (int nf = 0; nf < 2; nf++){
          int ec = j * 128 + wsc * 32 + nf * 16 + cl;
          #pragma unroll
          for (int rr = 0; rr < 4; rr++)
            ES[(er + rr) * EST2 + ec] = f2bf(acc[ih][j][mf][nf][rr]);
        }
      }
    __syncthreads();

    if (sec < 2){
      // rope: thread -> row r, head j, d-segment dbase
      const float fsc = (sec == 0) ? 0.12753375f : 1.0f;  // q: 1/sqrt(128)*log2e
      const int r = tid >> 2, cq = tid & 3;
      const int j = cq >> 1, dbase = (cq & 1) * 32;
      const int grow = m0 + ih * 128 + r;
      const int l = grow & (LL - 1);
      const float2* tab = rtab + l * 64 + dbase;
      const u16* srow = &ES[r * EST2 + j * 128];
      u16* orow = qk + (size_t)grow * QKN + n0 + j * 128;
      #pragma unroll
      for (int g = 0; g < 4; g++){
        bf16x8 x1v = *(const bf16x8*)(srow + dbase + g * 8);
        bf16x8 x2v = *(const bf16x8*)(srow + dbase + 64 + g * 8);
        bf16x8 o1, o2;
        #pragma unroll
        for (int i8 = 0; i8 < 8; i8++){
          float2 cs = tab[g * 8 + i8];
          float x1 = (float)x1v[i8], x2 = (float)x2v[i8];
          o1[i8] = (__bf16)((x1 * cs.x - x2 * cs.y) * fsc);
          o2[i8] = (__bf16)((x1 * cs.y + x2 * cs.x) * fsc);
        }
        *(bf16x8*)(orow + dbase + g * 8)      = o1;
        *(bf16x8*)(orow + dbase + 64 + g * 8) = o2;
      }
    } else {
      // v: thread -> column c (head j, dim d), l-half lh; write vt[bh][d][l]
      const int c = tid >> 1, lh = tid & 1;
      const int j = c >> 7, d = c & 127;
      const int grow0 = m0 + ih * 128;
      const int bh = ((grow0 >> 11) << 4) + (hd2 - 32 + j);
      u16* vrow = vt + ((size_t)bh * HDD + d) * LL + (grow0 & (LL - 1)) + lh * 64;
      #pragma unroll
      for (int g = 0; g < 8; g++){
        bf16x8 o;
        #pragma unroll
        for (int i8 = 0; i8 < 8; i8++)
          o[i8] = *(__bf16*)&ES[(lh * 64 + g * 8 + i8) * EST2 + c];
        *(bf16x8*)(vrow + g * 8) = o;
      }
    }
  }
}

// ---------------- GEMM 128x256 counted-vmcnt (proven for gemm2) ----------------

#define G2_STAGE(kt, bsel) do {                                                           \
  _Pragma("unroll")                                                                       \
  for (int i_ = 0; i_ < 2; i_++){     /* A: 128x64 = 1024 chunks */                       \
    int c_ = ((i_ * 8 + wv) * 64) + lane;                                                 \
    int p_ = c_ * 16;                                                                     \
    int r_ = p_ >> 7; int cb_ = (p_ & 127) ^ ((r_ & 7) << 4);                             \
    gl_lds16(A + (size_t)(m0 + r_) * K + (kt) + (cb_ >> 1),                               \
             &AB[bsel][((i_ * 8 + wv) * 64) * 8]);                                        \
  }                                                                                       \
  _Pragma("unroll")                                                                       \
  for (int i_ = 0; i_ < 4; i_++){     /* B: 256x64 = 2048 chunks */                       \
    int c_ = ((i_ * 8 + wv) * 64) + lane;                                                 \
    int p_ = c_ * 16;                                                                     \
    int r_ = p_ >> 7; int cb_ = (p_ & 127) ^ ((r_ & 7) << 4);                             \
    gl_lds16(Bt + (size_t)(n0 + r_) * K + (kt) + (cb_ >> 1),                              \
             &AB[bsel][8192 + ((i_ * 8 + wv) * 64) * 8]);                                 \
  }                                                                                       \
} while(0)

template<int OUT_BF16>
__global__ __launch_bounds__(512, 1) void gemm_bt2_k(
    const u16* __restrict__ A, const u16* __restrict__ Bt,
    void* __restrict__ Cout, int M, int N, int K)
{
  __shared__ __align__(16) u16 AB[2][24576];   // per buf: A[128][64] @0, B[256][64] @8192
  const int tid = threadIdx.x, lane = tid & 63, wv = tid >> 6;
  const int wr = wv >> 2, wc = wv & 3;          // 2 (M) x 4 (N) waves
  const int m0 = blockIdx.y * 128, n0 = blockIdx.x * 256;
  const int rq = lane >> 4, cl = lane & 15;
  const int NT = K >> 6;                        // 64-wide K tiles

  const f32x4 Z = {0.f, 0.f, 0.f, 0.f};
  f32x4 acc[4][4];
  #pragma unroll
  for (int m = 0; m < 4; m++)
    #pragma unroll
    for (int n = 0; n < 4; n++) acc[m][n] = Z;

  G2_STAGE(0, 0);
  G2_STAGE(64, 1);
  asm volatile("s_waitcnt vmcnt(6)");
  __builtin_amdgcn_sched_barrier(0);
  __builtin_amdgcn_s_barrier();

  int cur = 0;
  for (int t = 0; t < NT; t++){
    const char* As_ = (const char*)&AB[cur][0];
    const char* Bs_ = (const char*)&AB[cur][8192];

    #pragma unroll
    for (int ks = 0; ks < 2; ks++){
      const int kb = ks * 64 + rq * 16;
      bf16x8 a[4], b[4];
      #pragma unroll
      for (int m = 0; m < 4; m++){
        int r = wr * 64 + m * 16 + cl;
        a[m] = *(const bf16x8*)(As_ + r * 128 + (kb ^ ((r & 7) << 4)));
      }
      #pragma unroll
      for (int n = 0; n < 4; n++){
        int r = wc * 64 + n * 16 + cl;
        b[n] = *(const bf16x8*)(Bs_ + r * 128 + (kb ^ ((r & 7) << 4)));
      }
      __builtin_amdgcn_s_setprio(1);
      #pragma unroll
      for (int m = 0; m < 4; m++)
        #pragma unroll
        for (int n = 0; n < 4; n++)
          acc[m][n] = __builtin_amdgcn_mfma_f32_16x16x32_bf16(a[m], b[n], acc[m][n], 0, 0, 0);
      __builtin_amdgcn_s_setprio(0);
    }

    __builtin_amdgcn_sched_barrier(0);
    __builtin_amdgcn_s_barrier();              // every wave done READING buf[cur]

    if (t + 2 < NT){
      G2_STAGE((t + 2) * 64, cur);             // overwrite freed buffer
      asm volatile("s_waitcnt vmcnt(6)");      // tile t+1 landed; t+2 stays in flight
    } else {
      asm volatile("s_waitcnt vmcnt(0)");      // tail: drain remaining
    }
    __builtin_amdgcn_sched_barrier(0);
    __builtin_amdgcn_s_barrier();              // every wave's tile t+1 landed
    cur ^= 1;
  }

  #pragma unroll
  for (int m = 0; m < 4; m++){
    int gr0 = m0 + wr * 64 + m * 16 + rq * 4;
    #pragma unroll
    for (int n = 0; n < 4; n++){
      int gc = n0 + wc * 64 + n * 16 + cl;
      #pragma unroll
      for (int rr = 0; rr < 4; rr++){
        if (OUT_BF16) ((u16*)Cout)[(size_t)(gr0 + rr) * N + gc] = f2bf(acc[m][n][rr]);
        else          ((float*)Cout)[(size_t)(gr0 + rr) * N + gc] = acc[m][n][rr];
      }
    }
  }
}

// ---------------- flash attention v6 (r15-proven): deep K+V prefetch ----------

#define STAGE_K(jj, bsel) do {                                                            \
  _Pragma("unroll")                                                                       \
  for (int i_ = 0; i_ < 4; i_++){                                                         \
    int fb_ = (i_ * 4 + wv) * 64;                                                         \
    int p_  = (fb_ + lane) * 16;                                                          \
    int r_ = p_ >> 8; int cb_ = (p_ & 255) ^ ((r_ & 7) << 4);                             \
    gl_lds16(qk + (size_t)(b * LL + (jj) * 64 + r_) * QKN + 2048 + h * HDD + (cb_ >> 1),  \
             &Kb[bsel][fb_ * 8]);                                                         \
  }                                                                                       \
} while(0)

#define STAGE_V(jj, bsel) do {                                                            \
  _Pragma("unroll")                                                                       \
  for (int i_ = 0; i_ < 4; i_++){                                                         \
    int fb_ = (i_ * 4 + wv) * 64;                                                         \
    int p_  = (fb_ + lane) * 16;                                                          \
    int r_ = p_ >> 7; int cb_ = (p_ & 127) ^ ((r_ & 7) << 4);                             \
    gl_lds16(vt + (size_t)(bh * HDD + r_) * LL + (jj) * 64 + (cb_ >> 1),                  \
             &Vb[bsel][fb_ * 8]);                                                         \
  }                                                                                       \
} while(0)

__global__ __launch_bounds__(256, 2) void attn_k(
    const u16* __restrict__ qk, const u16* __restrict__ vt,
    u16* __restrict__ aout)
{
  __shared__ __align__(16) u16 Kb[2][64 * 128];   // K tiles, 2x16KB
  __shared__ __align__(16) u16 Vb[2][128 * 64];   // V^T tiles, 2x16KB
  __shared__ __align__(16) u16 Ps[4][1024];       // per-wave P tile 16x64, 8KB
  const int tid = threadIdx.x, lane = tid & 63, wv = tid >> 6;
  const int bh = blockIdx.x;                      // fast dim -> XCD = bh % 8
  const int pr = blockIdx.y;                      // pair index 0..15
  const int b = bh >> 4, h = bh & 15;
  const int rq = lane >> 4, cl = lane & 15;

  bf16x8 ones;
  #pragma unroll
  for (int i = 0; i < 8; i++) ones[i] = (__bf16)1.0f;
  const f32x4 Z = {0.f, 0.f, 0.f, 0.f};

  int cur = 0;
  STAGE_V(0, 0);                                  // phase-A tile 0 (V older in queue)
  STAGE_K(0, 0);

  #pragma unroll
  for (int ph = 0; ph < 2; ph++){
    const int qt = ph ? pr : (31 - pr);           // 64-row q-tile index
    const int nj = qt + 1;

    bf16x8 qf[4];
    {
      const u16* qb = qk + (size_t)(b * LL + qt * 64 + wv * 16 + cl) * QKN + h * HDD + rq * 8;
      #pragma unroll
      for (int ks = 0; ks < 4; ks++) qf[ks] = *(const bf16x8*)(qb + ks * 32);
    }

    f32x4 acco[8], accl;
    float mst[4];
    #pragma unroll
    for (int n = 0; n < 8; n++) acco[n] = Z;
    accl = Z;
    #pragma unroll
    for (int rr = 0; rr < 4; rr++) mst[rr] = -INFINITY;

    for (int j = 0; j < nj; j++){
      const bool sn = (j + 1 < nj) || (ph == 0);  // stages a next tile this iter
      if (j + 1 < nj){      STAGE_V(j + 1, cur ^ 1); STAGE_K(j + 1, cur ^ 1); }
      else if (ph == 0){    STAGE_V(0,     cur ^ 1); STAGE_K(0,     cur ^ 1); }
      __builtin_amdgcn_sched_barrier(0);
      if (sn) asm volatile("s_waitcnt vmcnt(8)" ::: "memory");  // tile j fully landed
      else    asm volatile("s_waitcnt vmcnt(0)" ::: "memory");
      __builtin_amdgcn_sched_barrier(0);
      __builtin_amdgcn_s_barrier();               // all waves' K(j),V(j) landed
      __builtin_amdgcn_sched_barrier(0);

      // S = Q K^T (16 q-rows x 64 kv per wave)
      f32x4 sv[4];
      {
        const char* KsC = (const char*)&Kb[cur][0];
        #pragma unroll
        for (int ct = 0; ct < 4; ct++) sv[ct] = Z;
        #pragma unroll
        for (int ks = 0; ks < 4; ks++){
          const int kb = ks * 64 + rq * 16;
          #pragma unroll
          for (int ct = 0; ct < 4; ct++){
            int r = ct * 16 + cl;
            bf16x8 bfr = *(const bf16x8*)(KsC + r * 256 + (kb ^ ((r & 7) << 4)));
            sv[ct] = __builtin_amdgcn_mfma_f32_16x16x32_bf16(qf[ks], bfr, sv[ct], 0, 0, 0);
          }
        }
      }

      // softmax (exp2 domain) + P write into own Ps slot (in-wave RAW ordering)
      {
        char* pbase = (char*)&Ps[wv][0];
        const bool msk = (j == qt);                 // diagonal tile only

        float p4[4][4], lmx[4];
        #pragma unroll
        for (int rr = 0; rr < 4; rr++) lmx[rr] = -1e30f;
        const int qg = qt * 64 + wv * 16 + rq * 4;
        #pragma unroll
        for (int ct = 0; ct < 4; ct++){
          int col = j * 64 + ct * 16 + cl;
          #pragma unroll
          for (int rr = 0; rr < 4; rr++){
            float v = sv[ct][rr];                   // already log2-domain
            if (msk && col > qg + rr) v = -1e30f;
            p4[ct][rr] = v;
            lmx[rr] = fmaxf(lmx[rr], v);
          }
        }
        float need = -1e30f;
        #pragma unroll
        for (int rr = 0; rr < 4; rr++) need = fmaxf(need, lmx[rr] - mst[rr]);
        if (__any(need > THR2)){
          float mx[4];
          #pragma unroll
          for (int rr = 0; rr < 4; rr++) mx[rr] = lmx[rr];
          #pragma unroll
          for (int off = 1; off < 16; off <<= 1)
            #pragma unroll
            for (int rr = 0; rr < 4; rr++)
              mx[rr] = fmaxf(mx[rr], __shfl_xor(mx[rr], off, 64));
          #pragma unroll
          for (int rr = 0; rr < 4; rr++){
            float mn  = fmaxf(mst[rr], mx[rr]);
            float fsc = exp2_fast(mst[rr] - mn);
            mst[rr] = mn;
            accl[rr] *= fsc;
            #pragma unroll
            for (int n = 0; n < 8; n++) acco[n][rr] *= fsc;
          }
        }
        #pragma unroll
        for (int ct = 0; ct < 4; ct++)
          #pragma unroll
          for (int rr = 0; rr < 4; rr++){
            float e = exp2_fast(p4[ct][rr] - mst[rr]);
            int wr = rq * 4 + rr;
            *(u16*)(pbase + wr * 128 + (((ct * 16 + cl) * 2) ^ ((wr & 7) << 4))) = f2bf(e);
          }
      }

      // O += P V ; l += P 1  (V already resident; no mid-iter wait)
      {
        const char* VsC = (const char*)&Vb[cur][0];
        char* pbase = (char*)&Ps[wv][0];
        #pragma unroll
        for (int ks = 0; ks < 2; ks++){
          const int kvb = ks * 64 + rq * 16;
          bf16x8 pa = *(const bf16x8*)(pbase + cl * 128 + (kvb ^ ((cl & 7) << 4)));
          accl = __builtin_amdgcn_mfma_f32_16x16x32_bf16(pa, ones, accl, 0, 0, 0);
          #pragma unroll
          for (int n = 0; n < 8; n++){
            int r = n * 16 + cl;
            bf16x8 bfr = *(const bf16x8*)(VsC + r * 128 + (kvb ^ ((r & 7) << 4)));
            acco[n] = __builtin_amdgcn_mfma_f32_16x16x32_bf16(pa, bfr, acco[n], 0, 0, 0);
          }
        }
      }

      __builtin_amdgcn_sched_barrier(0);
      __builtin_amdgcn_s_barrier();               // reads of buf[cur] done before overwrite
      __builtin_amdgcn_sched_barrier(0);
      cur ^= 1;
    }

    // direct write-out
    #pragma unroll
    for (int rr = 0; rr < 4; rr++){
      float inv = 1.0f / accl[rr];
      size_t grow = (size_t)(b * LL + qt * 64 + wv * 16 + rq * 4 + rr);
      #pragma unroll
      for (int n = 0; n < 8; n++)
        aout[grow * HIDD + h * HDD + n * 16 + cl] = f2bf(acco[n][rr] * inv);
    }
  }
}

// ---------------- launcher ----------------

extern "C" void kernel_launch(void* const* d_in, const int* in_sizes, int n_in,
                              void* d_out, int out_size, void* d_ws, size_t ws_size,
                              hipStream_t stream)
{
  const float* x  = (const float*)d_in[0];
  // d_in[1] = mask (causal; applied analytically)
  const float* Wq = (const float*)d_in[2];
  const float* Wk = (const float*)d_in[3];
  const float* Wv = (const float*)d_in[4];
  const float* Wo = (const float*)d_in[5];
  float* out = (float*)d_out;

  if (ws_size < 120586240ull) return;  // need ~115 MB of scratch

  char* ws = (char*)d_ws;
  u16*    xb   = (u16*)(ws);                   // 4096x2048 bf16   (16 MB)
  u16*    Wt   = (u16*)(ws + 16777216ull);     // 6144x2048 bf16   (24 MB) = [Wq|Wk|Wv]^T
  u16*    Wot  = (u16*)(ws + 41943040ull);     // 2048x2048 bf16   ( 8 MB)
  u16*    qk   = (u16*)(ws + 50331648ull);     // 4096x4096 bf16   (32 MB) roped q|k
  u16*    vt   = (u16*)(ws + 83886080ull);     // 32x128x2048 bf16 (16 MB)
  u16*    aout = (u16*)(ws + 100663296ull);    // 4096x2048 bf16   (16 MB)
  float2* rtab = (float2*)(ws + 117440512ull); // 2048x64 float2   ( 1 MB)

  cvt_f32_bf16_k<<<2097152 / 256, 256, 0, stream>>>(x, xb, 2097152);
  rope_table_k<<<131072 / 256, 256, 0, stream>>>(rtab);
  transpose_cvt4_k<<<dim3(32, 32, 4), 256, 0, stream>>>(Wq, Wk, Wv, Wo, Wt, Wot);

  gemm_qkv256_k<<<dim3(6144 / 256, 4096 / 256), 512, 0, stream>>>(xb, Wt, qk, vt, rtab, 2048);

  attn_k<<<dim3(32, 16), 256, 0, stream>>>(qk, vt, aout);

  gemm_bt2_k<0><<<dim3(2048 / 256, 4096 / 128), 512, 0, stream>>>(aout, Wot, out, 4096, 2048, 2048);
}